// Round 2
// baseline (1146.714 us; speedup 1.0000x reference)
//
#include <hip/hip_runtime.h>
#include <hip/hip_bf16.h>
#include <math.h>

typedef __attribute__((ext_vector_type(8))) short s16x8;
typedef __attribute__((ext_vector_type(4))) float f32x4;

#define T_TOK 16384
#define D_DIM 1024
#define F_DIM 2048
#define E_NUM 8
#define ROWCAP 33792  // 2*T_TOK + E_NUM*128 worst-case padded rows

__device__ __forceinline__ unsigned short f2b(float f) {
  unsigned u = __float_as_uint(f);
  u += 0x7fff + ((u >> 16) & 1);  // RNE
  return (unsigned short)(u >> 16);
}
__device__ __forceinline__ unsigned pk2(float a, float b) {
  __hip_bfloat162 h = __float22bfloat162_rn(make_float2(a, b));
  return *reinterpret_cast<unsigned*>(&h);
}
__device__ __forceinline__ void gload16(const void* g, void* l) {
  __builtin_amdgcn_global_load_lds(
      (const __attribute__((address_space(1))) unsigned*)g,
      (__attribute__((address_space(3))) unsigned*)l, 16, 0, 0);
}

// ---------------- weight cast fp32 -> bf16 (only if ws allows) ----------------
__global__ void castw_k(const float* __restrict__ w1, const float* __restrict__ w2,
                        unsigned short* __restrict__ w1b, unsigned short* __restrict__ w2b) {
  size_t i = ((size_t)blockIdx.x * 256 + threadIdx.x) * 4;
  float4 a = *(const float4*)(w1 + i);
  float4 b = *(const float4*)(w2 + i);
  uint2 ua, ub;
  ua.x = pk2(a.x, a.y); ua.y = pk2(a.z, a.w);
  ub.x = pk2(b.x, b.y); ub.y = pk2(b.z, b.w);
  *(uint2*)(w1b + i) = ua;
  *(uint2*)(w2b + i) = ub;
}

// ---------------- router: fp32 logits, softmax, top-2 (no atomics) ----------------
__global__ void router_k(const float* __restrict__ x, const float* __restrict__ wr,
                         int* __restrict__ topi, float* __restrict__ topw,
                         float* __restrict__ probs8) {
  int tid = threadIdx.x, wid = tid >> 6, lane = tid & 63;
  int t = blockIdx.x * 4 + wid;
  const float* xr = x + (size_t)t * D_DIM;
  float4 xv[4];
#pragma unroll
  for (int i = 0; i < 4; ++i) xv[i] = *(const float4*)(xr + i * 256 + lane * 4);
  float logit[E_NUM];
#pragma unroll
  for (int e = 0; e < E_NUM; ++e) {
    const float* wrow = wr + e * D_DIM;
    float p = 0.f;
#pragma unroll
    for (int i = 0; i < 4; ++i) {
      float4 wv = *(const float4*)(wrow + i * 256 + lane * 4);
      p += xv[i].x * wv.x + xv[i].y * wv.y + xv[i].z * wv.z + xv[i].w * wv.w;
    }
    for (int s = 32; s; s >>= 1) p += __shfl_xor(p, s);
    logit[e] = p;
  }
  if (lane == 0) {
    float m = logit[0];
    for (int e = 1; e < E_NUM; ++e) m = fmaxf(m, logit[e]);
    float pr[E_NUM];
    float sum = 0.f;
    for (int e = 0; e < E_NUM; ++e) { pr[e] = expf(logit[e] - m); sum += pr[e]; }
    float inv = 1.f / sum;
    for (int e = 0; e < E_NUM; ++e) { pr[e] *= inv; probs8[t * 8 + e] = pr[e]; }
    int i0 = 0;
    for (int e = 1; e < E_NUM; ++e) if (pr[e] > pr[i0]) i0 = e;
    int i1 = (i0 == 0) ? 1 : 0;
    for (int e = 0; e < E_NUM; ++e) if (e != i0 && pr[e] > pr[i1]) i1 = e;
    float wsum = pr[i0] + pr[i1];
    topi[2 * t] = i0;  topi[2 * t + 1] = i1;
    topw[2 * t] = pr[i0] / wsum;  topw[2 * t + 1] = pr[i1] / wsum;
  }
}

// ---------------- histogram: expert counts + usage sums (LDS-aggregated) ----------------
__global__ void hist_k(const int* __restrict__ topi, const float* __restrict__ probs8,
                       int* __restrict__ cnt, float* __restrict__ usage) {
  __shared__ int sc[E_NUM];
  __shared__ float su[E_NUM];
  int tid = threadIdx.x;
  if (tid < E_NUM) { sc[tid] = 0; su[tid] = 0.f; }
  __syncthreads();
  for (int i = blockIdx.x * 256 + tid; i < 2 * T_TOK; i += 256 * 64)
    atomicAdd(&sc[topi[i]], 1);
  for (int i = blockIdx.x * 256 + tid; i < 8 * T_TOK; i += 256 * 64)
    atomicAdd(&su[i & 7], probs8[i]);
  __syncthreads();
  if (tid < E_NUM) { atomicAdd(&cnt[tid], sc[tid]); atomicAdd(&usage[tid], su[tid]); }
}

// ---------------- offsets (128-padded) + aux loss ----------------
__global__ void scan_k(const int* __restrict__ cnt, int* __restrict__ offs,
                       const float* __restrict__ usage, float* __restrict__ aux) {
  if (threadIdx.x == 0 && blockIdx.x == 0) {
    int o = 0;
    for (int e = 0; e < E_NUM; ++e) { offs[e] = o; o += (cnt[e] + 127) & ~127; }
    offs[E_NUM] = o;
    float s = 0.f;
    for (int e = 0; e < E_NUM; ++e) { float m = usage[e] * (1.f / T_TOK); s += m * m; }
    *aux = (float)E_NUM * s;
  }
}

// ---------------- assignment: pair -> row (wave-aggregated atomics) ----------------
__global__ void assign_k(const int* __restrict__ topi, const int* __restrict__ offs,
                         int* __restrict__ cur, int* __restrict__ rowpair) {
  int p = blockIdx.x * 256 + threadIdx.x;
  int lane = threadIdx.x & 63;
  int e = topi[p];
  int r = 0;
#pragma unroll
  for (int ee = 0; ee < E_NUM; ++ee) {
    unsigned long long mask = __ballot(e == ee);
    if (e == ee) {
      int leader = __ffsll((unsigned long long)mask) - 1;
      int rank = __popcll(mask & ((1ull << lane) - 1ull));
      int b = 0;
      if (lane == leader) b = atomicAdd(&cur[ee], (int)__popcll(mask));
      b = __shfl(b, leader);
      r = offs[ee] + b + rank;
    }
  }
  rowpair[r] = p;
}

// ---------------- GEMM1: Hseg = gelu(gather(x) @ w1[e]^T), bf16 out ----------------
template <bool BPRE>
__global__ __launch_bounds__(256) void gemm1_k(
    const float* __restrict__ x, const void* __restrict__ w1v,
    const int* __restrict__ offs, const int* __restrict__ rowpair,
    unsigned short* __restrict__ hseg, int segbase, int segrows) {
  int bid = blockIdx.x;
  int e = bid >> 11, rem = bid & 2047, mt = rem >> 4, nt = rem & 15;
  int rend = offs[e + 1];
  int rowbase = offs[e] + mt * 128;
  if (rowbase >= rend || rowbase < segbase || rowbase >= segbase + segrows) return;

  __shared__ short As[128 * 64];
  __shared__ short Bs[128 * 64];
  __shared__ int s_tok[128];
  int tid = threadIdx.x, wid = tid >> 6, lane = tid & 63;
  int wm = wid >> 1, wn = wid & 1;
  if (tid < 128) { int p = rowpair[rowbase + tid]; s_tok[tid] = p >= 0 ? (p >> 1) : -1; }
  __syncthreads();

  int g4 = lane >> 4, c4 = (lane & 15) * 4;
  int srow = lane >> 3, scol = (lane & 7) * 8;
  int tok[8];
#pragma unroll
  for (int i = 0; i < 8; ++i) tok[i] = s_tok[i * 16 + wid * 4 + g4];

  const float* Bgf = (const float*)w1v + ((size_t)e * F_DIM + nt * 128) * D_DIM;
  const unsigned short* Bgb = (const unsigned short*)w1v + ((size_t)e * F_DIM + nt * 128) * D_DIM;

  f32x4 acc[4][4] = {};
  for (int ks = 0; ks < 16; ++ks) {
    int k0 = ks * 64;
    if (BPRE) {
#pragma unroll
      for (int i = 0; i < 4; ++i) {
        int chunk = i * 4 + wid;
        int row = chunk * 8 + srow;
        gload16(Bgb + (size_t)row * D_DIM + k0 + scol, (short*)Bs + chunk * 512);
      }
    } else {
#pragma unroll
      for (int i = 0; i < 8; ++i) {
        int row = i * 16 + wid * 4 + g4;
        float4 w = *(const float4*)(Bgf + (size_t)row * D_DIM + k0 + c4);
        uint2 uw; uw.x = pk2(w.x, w.y); uw.y = pk2(w.z, w.w);
        *(uint2*)&Bs[row * 64 + c4] = uw;
      }
    }
#pragma unroll
    for (int i = 0; i < 8; ++i) {
      int row = i * 16 + wid * 4 + g4;
      int t = tok[i];
      float4 v = make_float4(0.f, 0.f, 0.f, 0.f);
      if (t >= 0) v = *(const float4*)(x + (size_t)t * D_DIM + k0 + c4);
      uint2 u; u.x = pk2(v.x, v.y); u.y = pk2(v.z, v.w);
      *(uint2*)&As[row * 64 + c4] = u;
    }
    __syncthreads();
    int ar = wm * 64 + (lane & 15), br = wn * 64 + (lane & 15);
    int k8 = g4 * 8;
#pragma unroll
    for (int kk = 0; kk < 2; ++kk) {
      s16x8 a[4], b[4];
#pragma unroll
      for (int m = 0; m < 4; ++m) a[m] = *(const s16x8*)&As[(ar + m * 16) * 64 + kk * 32 + k8];
#pragma unroll
      for (int n = 0; n < 4; ++n) b[n] = *(const s16x8*)&Bs[(br + n * 16) * 64 + kk * 32 + k8];
#pragma unroll
      for (int m = 0; m < 4; ++m)
#pragma unroll
        for (int n = 0; n < 4; ++n)
          acc[m][n] = __builtin_amdgcn_mfma_f32_16x16x32_bf16(a[m], b[n], acc[m][n], 0, 0, 0);
    }
    __syncthreads();
  }
  int c0 = nt * 128 + wn * 64 + (lane & 15);
  int lr0 = wm * 64 + (g4 << 2);
  size_t rloc = (size_t)(rowbase - segbase);
#pragma unroll
  for (int m = 0; m < 4; ++m)
#pragma unroll
    for (int j = 0; j < 4; ++j) {
      size_t rr = (rloc + lr0 + m * 16 + j) * F_DIM;
#pragma unroll
      for (int n = 0; n < 4; ++n) {
        float v = acc[m][n][j];
        float g = 0.5f * v * (1.f + erff(v * 0.70710678118f));
        hseg[rr + c0 + n * 16] = f2b(g);
      }
    }
}

// ---------------- GEMM2: scatter-add w * (Hseg @ w2[e]^T) into out ----------------
template <bool BPRE>
__global__ __launch_bounds__(256) void gemm2_k(
    const unsigned short* __restrict__ hseg, const void* __restrict__ w2v,
    const int* __restrict__ offs, const int* __restrict__ rowpair,
    const float* __restrict__ topw, float* __restrict__ out,
    int segbase, int segrows) {
  int bid = blockIdx.x;
  int e = bid >> 10, rem = bid & 1023, mt = rem >> 3, nt = rem & 7;
  int rend = offs[e + 1];
  int rowbase = offs[e] + mt * 128;
  if (rowbase >= rend || rowbase < segbase || rowbase >= segbase + segrows) return;

  __shared__ short As[128 * 64];
  __shared__ short Bs[128 * 64];
  __shared__ int s_p[128];
  __shared__ float s_w[128];
  int tid = threadIdx.x, wid = tid >> 6, lane = tid & 63;
  int wm = wid >> 1, wn = wid & 1;
  if (tid < 128) {
    int p = rowpair[rowbase + tid];
    s_p[tid] = p;
    s_w[tid] = p >= 0 ? topw[p] : 0.f;
  }
  __syncthreads();

  int g4 = lane >> 4, c4 = (lane & 15) * 4;
  int srow = lane >> 3, scol = (lane & 7) * 8;
  const unsigned short* Ag = hseg + (size_t)(rowbase - segbase) * F_DIM;
  const float* Bgf = (const float*)w2v + ((size_t)e * D_DIM + nt * 128) * F_DIM;
  const unsigned short* Bgb = (const unsigned short*)w2v + ((size_t)e * D_DIM + nt * 128) * F_DIM;

  f32x4 acc[4][4] = {};
  for (int ks = 0; ks < 32; ++ks) {
    int k0 = ks * 64;
#pragma unroll
    for (int i = 0; i < 4; ++i) {
      int chunk = i * 4 + wid;
      int row = chunk * 8 + srow;
      gload16(Ag + (size_t)row * F_DIM + k0 + scol, (short*)As + chunk * 512);
    }
    if (BPRE) {
#pragma unroll
      for (int i = 0; i < 4; ++i) {
        int chunk = i * 4 + wid;
        int row = chunk * 8 + srow;
        gload16(Bgb + (size_t)row * F_DIM + k0 + scol, (short*)Bs + chunk * 512);
      }
    } else {
#pragma unroll
      for (int i = 0; i < 8; ++i) {
        int row = i * 16 + wid * 4 + g4;
        float4 w = *(const float4*)(Bgf + (size_t)row * F_DIM + k0 + c4);
        uint2 uw; uw.x = pk2(w.x, w.y); uw.y = pk2(w.z, w.w);
        *(uint2*)&Bs[row * 64 + c4] = uw;
      }
    }
    __syncthreads();
    int ar = wm * 64 + (lane & 15), br = wn * 64 + (lane & 15);
    int k8 = g4 * 8;
#pragma unroll
    for (int kk = 0; kk < 2; ++kk) {
      s16x8 a[4], b[4];
#pragma unroll
      for (int m = 0; m < 4; ++m) a[m] = *(const s16x8*)&As[(ar + m * 16) * 64 + kk * 32 + k8];
#pragma unroll
      for (int n = 0; n < 4; ++n) b[n] = *(const s16x8*)&Bs[(br + n * 16) * 64 + kk * 32 + k8];
#pragma unroll
      for (int m = 0; m < 4; ++m)
#pragma unroll
        for (int n = 0; n < 4; ++n)
          acc[m][n] = __builtin_amdgcn_mfma_f32_16x16x32_bf16(a[m], b[n], acc[m][n], 0, 0, 0);
    }
    __syncthreads();
  }
  int c0 = nt * 128 + wn * 64 + (lane & 15);
  int lr0 = wm * 64 + (g4 << 2);
#pragma unroll
  for (int m = 0; m < 4; ++m)
#pragma unroll
    for (int j = 0; j < 4; ++j) {
      int lr = lr0 + m * 16 + j;
      int p = s_p[lr];
      if (p >= 0) {
        float wgt = s_w[lr];
        int t = p >> 1;
        float* op = out + (size_t)t * D_DIM + c0;
#pragma unroll
        for (int n = 0; n < 4; ++n) unsafeAtomicAdd(op + n * 16, wgt * acc[m][n][j]);
      }
    }
}

extern "C" void kernel_launch(void* const* d_in, const int* in_sizes, int n_in,
                              void* d_out, int out_size, void* d_ws, size_t ws_size,
                              hipStream_t stream) {
  const float* x  = (const float*)d_in[0];
  const float* wr = (const float*)d_in[1];
  const float* w1 = (const float*)d_in[2];
  const float* w2 = (const float*)d_in[3];
  float* out = (float*)d_out;

  char* ws = (char*)d_ws;
  int* cnt = (int*)ws;                 // [8]
  int* cur = cnt + 8;                  // [8]
  int* offs = cnt + 16;                // [9]
  float* usage = (float*)(cnt + 25);   // [8]
  size_t off = 256;
  int*   topi = (int*)(ws + off);     off += (size_t)2 * T_TOK * 4;
  float* topw = (float*)(ws + off);   off += (size_t)2 * T_TOK * 4;
  int*   rowpair = (int*)(ws + off);  off += (size_t)ROWCAP * 4;
  float* probs8 = (float*)(ws + off); off += (size_t)T_TOK * 8 * 4;
  off = (off + 255) & ~(size_t)255;

  size_t wbytes = (size_t)2 * E_NUM * F_DIM * D_DIM * 2;  // 67.1 MB for w1b+w2b
  size_t avail = ws_size > off ? ws_size - off : 0;
  bool pre = false;
  unsigned short *w1b = nullptr, *w2b = nullptr;
  if (avail >= wbytes + (size_t)4096 * F_DIM * 2) {
    pre = true;
    w1b = (unsigned short*)(ws + off); off += wbytes / 2;
    w2b = (unsigned short*)(ws + off); off += wbytes / 2;
    avail -= wbytes;
  }
  size_t segcap = (avail / ((size_t)F_DIM * 2)) & ~(size_t)127;
  int segrows = segcap > (size_t)ROWCAP ? ROWCAP : (int)segcap;
  if (segrows < 512) return;  // workspace hopelessly small
  unsigned short* hseg = (unsigned short*)(ws + off);
  int nseg = (ROWCAP + segrows - 1) / segrows;

  hipMemsetAsync(ws, 0, 256, stream);
  hipMemsetAsync(rowpair, 0xFF, (size_t)ROWCAP * 4, stream);
  hipMemsetAsync(d_out, 0, (size_t)out_size * 4, stream);
  router_k<<<T_TOK / 4, 256, 0, stream>>>(x, wr, topi, topw, probs8);
  hist_k<<<64, 256, 0, stream>>>(topi, probs8, cnt, usage);
  scan_k<<<1, 64, 0, stream>>>(cnt, offs, usage, out + (size_t)T_TOK * D_DIM);
  assign_k<<<2 * T_TOK / 256, 256, 0, stream>>>(topi, offs, cur, rowpair);
  if (pre) castw_k<<<16384, 256, 0, stream>>>(w1, w2, w1b, w2b);

  for (int s = 0; s < nseg; ++s) {
    int segbase = s * segrows;
    if (pre) {
      gemm1_k<true><<<E_NUM * 128 * 16, 256, 0, stream>>>(x, w1b, offs, rowpair, hseg, segbase, segrows);
      gemm2_k<true><<<E_NUM * 128 * 8, 256, 0, stream>>>(hseg, w2b, offs, rowpair, topw, out, segbase, segrows);
    } else {
      gemm1_k<false><<<E_NUM * 128 * 16, 256, 0, stream>>>(x, w1, offs, rowpair, hseg, segbase, segrows);
      gemm2_k<false><<<E_NUM * 128 * 8, 256, 0, stream>>>(hseg, w2, offs, rowpair, topw, out, segbase, segrows);
    }
  }
}

// Round 3
// 1026.476 us; speedup vs baseline: 1.1171x; 1.1171x over previous
//
#include <hip/hip_runtime.h>
#include <hip/hip_bf16.h>
#include <math.h>

typedef __attribute__((ext_vector_type(8))) short s16x8;
typedef __attribute__((ext_vector_type(4))) float f32x4;

#define T_TOK 16384
#define D_DIM 1024
#define F_DIM 2048
#define E_NUM 8
#define ROWCAP 33792  // 2*T_TOK + E_NUM*128 worst-case padded rows

__device__ __forceinline__ unsigned short f2b(float f) {
  unsigned u = __float_as_uint(f);
  u += 0x7fff + ((u >> 16) & 1);  // RNE
  return (unsigned short)(u >> 16);
}
__device__ __forceinline__ unsigned pk2(float a, float b) {
  __hip_bfloat162 h = __float22bfloat162_rn(make_float2(a, b));
  return *reinterpret_cast<unsigned*>(&h);
}
__device__ __forceinline__ void gload16(const void* g, void* l) {
  __builtin_amdgcn_global_load_lds(
      (const __attribute__((address_space(1))) unsigned*)g,
      (__attribute__((address_space(3))) unsigned*)l, 16, 0, 0);
}

// ---------------- weight cast fp32 -> bf16 (tier A) ----------------
__global__ void castw_k(const float* __restrict__ w1, const float* __restrict__ w2,
                        unsigned short* __restrict__ w1b, unsigned short* __restrict__ w2b) {
  size_t i = ((size_t)blockIdx.x * 256 + threadIdx.x) * 4;
  float4 a = *(const float4*)(w1 + i);
  float4 b = *(const float4*)(w2 + i);
  uint2 ua, ub;
  ua.x = pk2(a.x, a.y); ua.y = pk2(a.z, a.w);
  ub.x = pk2(b.x, b.y); ub.y = pk2(b.z, b.w);
  *(uint2*)(w1b + i) = ua;
  *(uint2*)(w2b + i) = ub;
}

// ---------------- router: fp32 logits, softmax, top-2 ----------------
__global__ void router_k(const float* __restrict__ x, const float* __restrict__ wr,
                         int* __restrict__ topi, float* __restrict__ topw,
                         float* __restrict__ probs8) {
  int tid = threadIdx.x, wid = tid >> 6, lane = tid & 63;
  int t = blockIdx.x * 4 + wid;
  const float* xr = x + (size_t)t * D_DIM;
  float4 xv[4];
#pragma unroll
  for (int i = 0; i < 4; ++i) xv[i] = *(const float4*)(xr + i * 256 + lane * 4);
  float logit[E_NUM];
#pragma unroll
  for (int e = 0; e < E_NUM; ++e) {
    const float* wrow = wr + e * D_DIM;
    float p = 0.f;
#pragma unroll
    for (int i = 0; i < 4; ++i) {
      float4 wv = *(const float4*)(wrow + i * 256 + lane * 4);
      p += xv[i].x * wv.x + xv[i].y * wv.y + xv[i].z * wv.z + xv[i].w * wv.w;
    }
    for (int s = 32; s; s >>= 1) p += __shfl_xor(p, s);
    logit[e] = p;
  }
  if (lane == 0) {
    float m = logit[0];
    for (int e = 1; e < E_NUM; ++e) m = fmaxf(m, logit[e]);
    float pr[E_NUM];
    float sum = 0.f;
    for (int e = 0; e < E_NUM; ++e) { pr[e] = expf(logit[e] - m); sum += pr[e]; }
    float inv = 1.f / sum;
    for (int e = 0; e < E_NUM; ++e) { pr[e] *= inv; probs8[t * 8 + e] = pr[e]; }
    int i0 = 0;
    for (int e = 1; e < E_NUM; ++e) if (pr[e] > pr[i0]) i0 = e;
    int i1 = (i0 == 0) ? 1 : 0;
    for (int e = 0; e < E_NUM; ++e) if (e != i0 && pr[e] > pr[i1]) i1 = e;
    float wsum = pr[i0] + pr[i1];
    topi[2 * t] = i0;  topi[2 * t + 1] = i1;
    topw[2 * t] = pr[i0] / wsum;  topw[2 * t + 1] = pr[i1] / wsum;
  }
}

// ---------------- histogram: expert counts + usage sums ----------------
__global__ void hist_k(const int* __restrict__ topi, const float* __restrict__ probs8,
                       int* __restrict__ cnt, float* __restrict__ usage) {
  __shared__ int sc[E_NUM];
  __shared__ float su[E_NUM];
  int tid = threadIdx.x;
  if (tid < E_NUM) { sc[tid] = 0; su[tid] = 0.f; }
  __syncthreads();
  for (int i = blockIdx.x * 256 + tid; i < 2 * T_TOK; i += 256 * 64)
    atomicAdd(&sc[topi[i]], 1);
  for (int i = blockIdx.x * 256 + tid; i < 8 * T_TOK; i += 256 * 64)
    atomicAdd(&su[i & 7], probs8[i]);
  __syncthreads();
  if (tid < E_NUM) { atomicAdd(&cnt[tid], sc[tid]); atomicAdd(&usage[tid], su[tid]); }
}

// ---------------- offsets (128-padded) + aux loss ----------------
__global__ void scan_k(const int* __restrict__ cnt, int* __restrict__ offs,
                       const float* __restrict__ usage, float* __restrict__ aux) {
  if (threadIdx.x == 0 && blockIdx.x == 0) {
    int o = 0;
    for (int e = 0; e < E_NUM; ++e) { offs[e] = o; o += (cnt[e] + 127) & ~127; }
    offs[E_NUM] = o;
    float s = 0.f;
    for (int e = 0; e < E_NUM; ++e) { float m = usage[e] * (1.f / T_TOK); s += m * m; }
    *aux = (float)E_NUM * s;
  }
}

// ---------------- assignment: pair -> row ----------------
__global__ void assign_k(const int* __restrict__ topi, const int* __restrict__ offs,
                         int* __restrict__ cur, int* __restrict__ rowpair) {
  int p = blockIdx.x * 256 + threadIdx.x;
  int lane = threadIdx.x & 63;
  int e = topi[p];
  int r = 0;
#pragma unroll
  for (int ee = 0; ee < E_NUM; ++ee) {
    unsigned long long mask = __ballot(e == ee);
    if (e == ee) {
      int leader = __ffsll((unsigned long long)mask) - 1;
      int rank = __popcll(mask & ((1ull << lane) - 1ull));
      int b = 0;
      if (lane == leader) b = atomicAdd(&cur[ee], (int)__popcll(mask));
      b = __shfl(b, leader);
      r = offs[ee] + b + rank;
    }
  }
  rowpair[r] = p;
}

// ---------------- gather all padded rows -> bf16 xg (pads zeroed) ----------------
__global__ void gatherx_k(const float* __restrict__ x, const int* __restrict__ rowpair,
                          unsigned short* __restrict__ xg) {
  int wid = threadIdx.x >> 6, lane = threadIdx.x & 63;
  int r = blockIdx.x * 4 + wid;
  int p = rowpair[r];
  unsigned short* dst = xg + (size_t)r * D_DIM;
  if (p >= 0) {
    const float* src = x + (size_t)(p >> 1) * D_DIM;
#pragma unroll
    for (int i = 0; i < 4; ++i) {
      float4 v = *(const float4*)(src + i * 256 + lane * 4);
      uint2 u; u.x = pk2(v.x, v.y); u.y = pk2(v.z, v.w);
      *(uint2*)(dst + i * 256 + lane * 4) = u;
    }
  } else {
    uint2 z = {0u, 0u};
#pragma unroll
    for (int i = 0; i < 4; ++i) *(uint2*)(dst + i * 256 + lane * 4) = z;
  }
}

// ---------------- GEMM1 (fast A from xg): hseg = gelu(xg @ w1[e]^T) ----------------
template <bool BPRE>
__global__ __launch_bounds__(256) void gemm1x_k(
    const unsigned short* __restrict__ xg, const void* __restrict__ w1v,
    const int* __restrict__ offs, unsigned short* __restrict__ hseg,
    int segbase, int segrows) {
  int bid0 = blockIdx.x;
  int bid = ((bid0 & 7) << 11) | (bid0 >> 3);  // XCD chunk swizzle, grid=16384
  int e = bid >> 11, rem = bid & 2047, mt = rem >> 4, nt = rem & 15;
  int rend = offs[e + 1];
  int rowbase = offs[e] + mt * 128;
  if (rowbase >= rend || rowbase < segbase || rowbase >= segbase + segrows) return;

  __shared__ short As[128 * 64];
  __shared__ short Bs[128 * 64];
  int tid = threadIdx.x, wid = tid >> 6, lane = tid & 63;
  int wm = wid >> 1, wn = wid & 1;
  int g4 = lane >> 4, c4 = (lane & 15) * 4;
  int srow = lane >> 3, scol = (lane & 7) * 8;

  const unsigned short* Ag = xg + (size_t)rowbase * D_DIM;
  const float* Bgf = (const float*)w1v + ((size_t)e * F_DIM + nt * 128) * D_DIM;
  const unsigned short* Bgb = (const unsigned short*)w1v + ((size_t)e * F_DIM + nt * 128) * D_DIM;

  f32x4 acc[4][4] = {};
  for (int ks = 0; ks < 16; ++ks) {
    int k0 = ks * 64;
#pragma unroll
    for (int i = 0; i < 4; ++i) {
      int chunk = i * 4 + wid;
      int row = chunk * 8 + srow;
      gload16(Ag + (size_t)row * D_DIM + k0 + scol, (short*)As + chunk * 512);
    }
    if (BPRE) {
#pragma unroll
      for (int i = 0; i < 4; ++i) {
        int chunk = i * 4 + wid;
        int row = chunk * 8 + srow;
        gload16(Bgb + (size_t)row * D_DIM + k0 + scol, (short*)Bs + chunk * 512);
      }
    } else {
#pragma unroll
      for (int i = 0; i < 8; ++i) {
        int row = i * 16 + wid * 4 + g4;
        float4 w = *(const float4*)(Bgf + (size_t)row * D_DIM + k0 + c4);
        uint2 uw; uw.x = pk2(w.x, w.y); uw.y = pk2(w.z, w.w);
        *(uint2*)&Bs[row * 64 + c4] = uw;
      }
    }
    __syncthreads();
    int ar = wm * 64 + (lane & 15), br = wn * 64 + (lane & 15);
    int k8 = g4 * 8;
#pragma unroll
    for (int kk = 0; kk < 2; ++kk) {
      s16x8 a[4], b[4];
#pragma unroll
      for (int m = 0; m < 4; ++m) a[m] = *(const s16x8*)&As[(ar + m * 16) * 64 + kk * 32 + k8];
#pragma unroll
      for (int n = 0; n < 4; ++n) b[n] = *(const s16x8*)&Bs[(br + n * 16) * 64 + kk * 32 + k8];
#pragma unroll
      for (int m = 0; m < 4; ++m)
#pragma unroll
        for (int n = 0; n < 4; ++n)
          acc[m][n] = __builtin_amdgcn_mfma_f32_16x16x32_bf16(a[m], b[n], acc[m][n], 0, 0, 0);
    }
    __syncthreads();
  }
  int c0 = nt * 128 + wn * 64 + (lane & 15);
  int lr0 = wm * 64 + (g4 << 2);
  size_t rloc = (size_t)(rowbase - segbase);
#pragma unroll
  for (int m = 0; m < 4; ++m)
#pragma unroll
    for (int j = 0; j < 4; ++j) {
      size_t rr = (rloc + lr0 + m * 16 + j) * F_DIM;
#pragma unroll
      for (int n = 0; n < 4; ++n) {
        float v = acc[m][n][j];
        float g = 0.5f * v * (1.f + erff(v * 0.70710678118f));
        hseg[rr + c0 + n * 16] = f2b(g);
      }
    }
}

// ---------------- GEMM1 fallback (tier C): gather fp32 x inline ----------------
__global__ __launch_bounds__(256) void gemm1_slow_k(
    const float* __restrict__ x, const float* __restrict__ w1f,
    const int* __restrict__ offs, const int* __restrict__ rowpair,
    unsigned short* __restrict__ hseg, int segbase, int segrows) {
  int bid = blockIdx.x;
  int e = bid >> 11, rem = bid & 2047, mt = rem >> 4, nt = rem & 15;
  int rend = offs[e + 1];
  int rowbase = offs[e] + mt * 128;
  if (rowbase >= rend || rowbase < segbase || rowbase >= segbase + segrows) return;

  __shared__ short As[128 * 64];
  __shared__ short Bs[128 * 64];
  __shared__ int s_tok[128];
  int tid = threadIdx.x, wid = tid >> 6, lane = tid & 63;
  int wm = wid >> 1, wn = wid & 1;
  if (tid < 128) { int p = rowpair[rowbase + tid]; s_tok[tid] = p >= 0 ? (p >> 1) : -1; }
  __syncthreads();
  int g4 = lane >> 4, c4 = (lane & 15) * 4;
  int tok[8];
#pragma unroll
  for (int i = 0; i < 8; ++i) tok[i] = s_tok[i * 16 + wid * 4 + g4];
  const float* Bgf = w1f + ((size_t)e * F_DIM + nt * 128) * D_DIM;

  f32x4 acc[4][4] = {};
  for (int ks = 0; ks < 16; ++ks) {
    int k0 = ks * 64;
#pragma unroll
    for (int i = 0; i < 8; ++i) {
      int row = i * 16 + wid * 4 + g4;
      float4 w = *(const float4*)(Bgf + (size_t)row * D_DIM + k0 + c4);
      uint2 uw; uw.x = pk2(w.x, w.y); uw.y = pk2(w.z, w.w);
      *(uint2*)&Bs[row * 64 + c4] = uw;
      int t = tok[i];
      float4 v = make_float4(0.f, 0.f, 0.f, 0.f);
      if (t >= 0) v = *(const float4*)(x + (size_t)t * D_DIM + k0 + c4);
      uint2 u; u.x = pk2(v.x, v.y); u.y = pk2(v.z, v.w);
      *(uint2*)&As[row * 64 + c4] = u;
    }
    __syncthreads();
    int ar = wm * 64 + (lane & 15), br = wn * 64 + (lane & 15);
    int k8 = g4 * 8;
#pragma unroll
    for (int kk = 0; kk < 2; ++kk) {
      s16x8 a[4], b[4];
#pragma unroll
      for (int m = 0; m < 4; ++m) a[m] = *(const s16x8*)&As[(ar + m * 16) * 64 + kk * 32 + k8];
#pragma unroll
      for (int n = 0; n < 4; ++n) b[n] = *(const s16x8*)&Bs[(br + n * 16) * 64 + kk * 32 + k8];
#pragma unroll
      for (int m = 0; m < 4; ++m)
#pragma unroll
        for (int n = 0; n < 4; ++n)
          acc[m][n] = __builtin_amdgcn_mfma_f32_16x16x32_bf16(a[m], b[n], acc[m][n], 0, 0, 0);
    }
    __syncthreads();
  }
  int c0 = nt * 128 + wn * 64 + (lane & 15);
  int lr0 = wm * 64 + (g4 << 2);
  size_t rloc = (size_t)(rowbase - segbase);
#pragma unroll
  for (int m = 0; m < 4; ++m)
#pragma unroll
    for (int j = 0; j < 4; ++j) {
      size_t rr = (rloc + lr0 + m * 16 + j) * F_DIM;
#pragma unroll
      for (int n = 0; n < 4; ++n) {
        float v = acc[m][n][j];
        float g = 0.5f * v * (1.f + erff(v * 0.70710678118f));
        hseg[rr + c0 + n * 16] = f2b(g);
      }
    }
}

// ---------------- GEMM2: out[t] += w * (hseg @ w2[e]^T), atomic scatter ----------------
template <bool BPRE>
__global__ __launch_bounds__(256) void gemm2_k(
    const unsigned short* __restrict__ hseg, const void* __restrict__ w2v,
    const int* __restrict__ offs, const int* __restrict__ rowpair,
    const float* __restrict__ topw, float* __restrict__ out,
    int segbase, int segrows) {
  int bid0 = blockIdx.x;
  int bid = ((bid0 & 7) << 10) | (bid0 >> 3);  // XCD chunk swizzle, grid=8192
  int e = bid >> 10, rem = bid & 1023, mt = rem >> 3, nt = rem & 7;
  int rend = offs[e + 1];
  int rowbase = offs[e] + mt * 128;
  if (rowbase >= rend || rowbase < segbase || rowbase >= segbase + segrows) return;

  __shared__ short As[128 * 64];
  __shared__ short Bs[128 * 64];
  int tid = threadIdx.x, wid = tid >> 6, lane = tid & 63;
  int wm = wid >> 1, wn = wid & 1;
  int g4 = lane >> 4, c4 = (lane & 15) * 4;
  int srow = lane >> 3, scol = (lane & 7) * 8;

  const unsigned short* Ag = hseg + (size_t)(rowbase - segbase) * F_DIM;
  const float* Bgf = (const float*)w2v + ((size_t)e * D_DIM + nt * 128) * F_DIM;
  const unsigned short* Bgb = (const unsigned short*)w2v + ((size_t)e * D_DIM + nt * 128) * F_DIM;

  f32x4 acc[4][4] = {};
  for (int ks = 0; ks < 32; ++ks) {
    int k0 = ks * 64;
#pragma unroll
    for (int i = 0; i < 4; ++i) {
      int chunk = i * 4 + wid;
      int row = chunk * 8 + srow;
      gload16(Ag + (size_t)row * F_DIM + k0 + scol, (short*)As + chunk * 512);
    }
    if (BPRE) {
#pragma unroll
      for (int i = 0; i < 4; ++i) {
        int chunk = i * 4 + wid;
        int row = chunk * 8 + srow;
        gload16(Bgb + (size_t)row * F_DIM + k0 + scol, (short*)Bs + chunk * 512);
      }
    } else {
#pragma unroll
      for (int i = 0; i < 8; ++i) {
        int row = i * 16 + wid * 4 + g4;
        float4 w = *(const float4*)(Bgf + (size_t)row * F_DIM + k0 + c4);
        uint2 uw; uw.x = pk2(w.x, w.y); uw.y = pk2(w.z, w.w);
        *(uint2*)&Bs[row * 64 + c4] = uw;
      }
    }
    __syncthreads();
    int ar = wm * 64 + (lane & 15), br = wn * 64 + (lane & 15);
    int k8 = g4 * 8;
#pragma unroll
    for (int kk = 0; kk < 2; ++kk) {
      s16x8 a[4], b[4];
#pragma unroll
      for (int m = 0; m < 4; ++m) a[m] = *(const s16x8*)&As[(ar + m * 16) * 64 + kk * 32 + k8];
#pragma unroll
      for (int n = 0; n < 4; ++n) b[n] = *(const s16x8*)&Bs[(br + n * 16) * 64 + kk * 32 + k8];
#pragma unroll
      for (int m = 0; m < 4; ++m)
#pragma unroll
        for (int n = 0; n < 4; ++n)
          acc[m][n] = __builtin_amdgcn_mfma_f32_16x16x32_bf16(a[m], b[n], acc[m][n], 0, 0, 0);
    }
    __syncthreads();
  }
  int c0 = nt * 128 + wn * 64 + (lane & 15);
  int lr0 = wm * 64 + (g4 << 2);
#pragma unroll
  for (int m = 0; m < 4; ++m)
#pragma unroll
    for (int j = 0; j < 4; ++j) {
      int lr = lr0 + m * 16 + j;
      int p = rowpair[rowbase + lr];
      if (p >= 0) {
        float wgt = topw[p];
        float* op = out + (size_t)(p >> 1) * D_DIM + c0;
#pragma unroll
        for (int n = 0; n < 4; ++n) unsafeAtomicAdd(op + n * 16, wgt * acc[m][n][j]);
      }
    }
}

extern "C" void kernel_launch(void* const* d_in, const int* in_sizes, int n_in,
                              void* d_out, int out_size, void* d_ws, size_t ws_size,
                              hipStream_t stream) {
  const float* x  = (const float*)d_in[0];
  const float* wr = (const float*)d_in[1];
  const float* w1 = (const float*)d_in[2];
  const float* w2 = (const float*)d_in[3];
  float* out = (float*)d_out;

  char* ws = (char*)d_ws;
  int* cnt = (int*)ws;                 // [8]
  int* cur = cnt + 8;                  // [8]
  int* offs = cnt + 16;                // [9]
  float* usage = (float*)(cnt + 25);   // [8]
  size_t off = 256;
  int*   topi = (int*)(ws + off);     off += (size_t)2 * T_TOK * 4;
  float* topw = (float*)(ws + off);   off += (size_t)2 * T_TOK * 4;
  int*   rowpair = (int*)(ws + off);  off += (size_t)ROWCAP * 4;
  float* probs8 = (float*)(ws + off); off += (size_t)T_TOK * 8 * 4;
  off = (off + 255) & ~(size_t)255;

  const size_t xgbytes = (size_t)ROWCAP * D_DIM * 2;           // 69.2 MB
  const size_t wbytes  = (size_t)2 * E_NUM * F_DIM * D_DIM * 2; // 67.1 MB
  const size_t minseg  = (size_t)8448 * F_DIM * 2;              // 34.6 MB (nseg<=4)

  bool xgok = false, pre = false;
  unsigned short *xg = nullptr, *w1b = nullptr, *w2b = nullptr;
  if (ws_size >= off + xgbytes + (size_t)2 * 1024 * 1024) {
    xgok = true;
    xg = (unsigned short*)(ws + off); off += xgbytes;
  }
  if (xgok && ws_size >= off + wbytes + minseg) {
    pre = true;
    w1b = (unsigned short*)(ws + off); off += wbytes / 2;
    w2b = (unsigned short*)(ws + off); off += wbytes / 2;
  }
  size_t avail = ws_size - off;
  size_t segcap = (avail / ((size_t)F_DIM * 2)) & ~(size_t)127;
  int segrows = segcap > (size_t)ROWCAP ? ROWCAP : (int)segcap;
  if (segrows < 128) return;
  unsigned short* hseg = (unsigned short*)(ws + off);
  int nseg = (ROWCAP + segrows - 1) / segrows;

  hipMemsetAsync(ws, 0, 256, stream);
  hipMemsetAsync(rowpair, 0xFF, (size_t)ROWCAP * 4, stream);
  hipMemsetAsync(d_out, 0, (size_t)out_size * 4, stream);
  router_k<<<T_TOK / 4, 256, 0, stream>>>(x, wr, topi, topw, probs8);
  hist_k<<<64, 256, 0, stream>>>(topi, probs8, cnt, usage);
  scan_k<<<1, 64, 0, stream>>>(cnt, offs, usage, out + (size_t)T_TOK * D_DIM);
  assign_k<<<2 * T_TOK / 256, 256, 0, stream>>>(topi, offs, cur, rowpair);
  if (xgok) gatherx_k<<<ROWCAP / 4, 256, 0, stream>>>(x, rowpair, xg);
  if (pre)  castw_k<<<16384, 256, 0, stream>>>(w1, w2, w1b, w2b);

  for (int s = 0; s < nseg; ++s) {
    int segbase = s * segrows;
    if (xgok && pre) {
      gemm1x_k<true><<<E_NUM * 2048, 256, 0, stream>>>(xg, w1b, offs, hseg, segbase, segrows);
      gemm2_k<true><<<E_NUM * 1024, 256, 0, stream>>>(hseg, w2b, offs, rowpair, topw, out, segbase, segrows);
    } else if (xgok) {
      gemm1x_k<false><<<E_NUM * 2048, 256, 0, stream>>>(xg, w1, offs, hseg, segbase, segrows);
      gemm2_k<false><<<E_NUM * 1024, 256, 0, stream>>>(hseg, w2, offs, rowpair, topw, out, segbase, segrows);
    } else {
      gemm1_slow_k<<<E_NUM * 2048, 256, 0, stream>>>(x, w1, offs, rowpair, hseg, segbase, segrows);
      gemm2_k<false><<<E_NUM * 1024, 256, 0, stream>>>(hseg, w2, offs, rowpair, topw, out, segbase, segrows);
    }
  }
}

// Round 4
// 751.187 us; speedup vs baseline: 1.5265x; 1.3665x over previous
//
#include <hip/hip_runtime.h>
#include <hip/hip_bf16.h>
#include <math.h>

typedef __attribute__((ext_vector_type(8))) short s16x8;
typedef __attribute__((ext_vector_type(4))) float f32x4;

#define T_TOK 16384
#define D_DIM 1024
#define F_DIM 2048
#define E_NUM 8
#define ROWCAP 33792  // worst-case padded rows (2T + 8*128)

__device__ __forceinline__ unsigned pk2(float a, float b) {
  __hip_bfloat162 h = __float22bfloat162_rn(make_float2(a, b));
  return *reinterpret_cast<unsigned*>(&h);
}
__device__ __forceinline__ unsigned short f2b(float f) {
  unsigned u = __float_as_uint(f);
  u += 0x7fff + ((u >> 16) & 1);
  return (unsigned short)(u >> 16);
}
__device__ __forceinline__ void gload16(const void* g, void* l) {
  __builtin_amdgcn_global_load_lds(
      (const __attribute__((address_space(1))) unsigned*)g,
      (__attribute__((address_space(3))) unsigned*)l, 16, 0, 0);
}

// ---------------- cast x fp32 -> bf16 token-order ----------------
__global__ void castx_k(const float* __restrict__ x, unsigned short* __restrict__ xb) {
  size_t i = ((size_t)blockIdx.x * 256 + threadIdx.x) * 8;
  float4 a = *(const float4*)(x + i);
  float4 b = *(const float4*)(x + i + 4);
  uint4 u;
  u.x = pk2(a.x, a.y); u.y = pk2(a.z, a.w);
  u.z = pk2(b.x, b.y); u.w = pk2(b.z, b.w);
  *(uint4*)(xb + i) = u;
}

// ---------------- cast weights fp32 -> bf16 ----------------
__global__ void castw_k(const float* __restrict__ w1, const float* __restrict__ w2,
                        unsigned short* __restrict__ w1b, unsigned short* __restrict__ w2b) {
  size_t i = ((size_t)blockIdx.x * 256 + threadIdx.x) * 4;
  float4 a = *(const float4*)(w1 + i);
  float4 b = *(const float4*)(w2 + i);
  uint2 ua, ub;
  ua.x = pk2(a.x, a.y); ua.y = pk2(a.z, a.w);
  ub.x = pk2(b.x, b.y); ub.y = pk2(b.z, b.w);
  *(uint2*)(w1b + i) = ua;
  *(uint2*)(w2b + i) = ub;
}

// ---------------- router: fp32 logits, softmax, top-2 ----------------
__global__ void router_k(const float* __restrict__ x, const float* __restrict__ wr,
                         int* __restrict__ topi, float* __restrict__ topw,
                         float* __restrict__ probs8) {
  int tid = threadIdx.x, wid = tid >> 6, lane = tid & 63;
  int t = blockIdx.x * 4 + wid;
  const float* xr = x + (size_t)t * D_DIM;
  float4 xv[4];
#pragma unroll
  for (int i = 0; i < 4; ++i) xv[i] = *(const float4*)(xr + i * 256 + lane * 4);
  float logit[E_NUM];
#pragma unroll
  for (int e = 0; e < E_NUM; ++e) {
    const float* wrow = wr + e * D_DIM;
    float p = 0.f;
#pragma unroll
    for (int i = 0; i < 4; ++i) {
      float4 wv = *(const float4*)(wrow + i * 256 + lane * 4);
      p += xv[i].x * wv.x + xv[i].y * wv.y + xv[i].z * wv.z + xv[i].w * wv.w;
    }
    for (int s = 32; s; s >>= 1) p += __shfl_xor(p, s);
    logit[e] = p;
  }
  if (lane == 0) {
    float m = logit[0];
    for (int e = 1; e < E_NUM; ++e) m = fmaxf(m, logit[e]);
    float pr[E_NUM];
    float sum = 0.f;
    for (int e = 0; e < E_NUM; ++e) { pr[e] = expf(logit[e] - m); sum += pr[e]; }
    float inv = 1.f / sum;
    for (int e = 0; e < E_NUM; ++e) { pr[e] *= inv; probs8[t * 8 + e] = pr[e]; }
    int i0 = 0;
    for (int e = 1; e < E_NUM; ++e) if (pr[e] > pr[i0]) i0 = e;
    int i1 = (i0 == 0) ? 1 : 0;
    for (int e = 0; e < E_NUM; ++e) if (e != i0 && pr[e] > pr[i1]) i1 = e;
    float wsum = pr[i0] + pr[i1];
    topi[2 * t] = i0;  topi[2 * t + 1] = i1;
    topw[2 * t] = pr[i0] / wsum;  topw[2 * t + 1] = pr[i1] / wsum;
  }
}

// ---------------- histogram ----------------
__global__ void hist_k(const int* __restrict__ topi, const float* __restrict__ probs8,
                       int* __restrict__ cnt, float* __restrict__ usage) {
  __shared__ int sc[E_NUM];
  __shared__ float su[E_NUM];
  int tid = threadIdx.x;
  if (tid < E_NUM) { sc[tid] = 0; su[tid] = 0.f; }
  __syncthreads();
  for (int i = blockIdx.x * 256 + tid; i < 2 * T_TOK; i += 256 * 64)
    atomicAdd(&sc[topi[i]], 1);
  for (int i = blockIdx.x * 256 + tid; i < 8 * T_TOK; i += 256 * 64)
    atomicAdd(&su[i & 7], probs8[i]);
  __syncthreads();
  if (tid < E_NUM) { atomicAdd(&cnt[tid], sc[tid]); atomicAdd(&usage[tid], su[tid]); }
}

// ---------------- offsets + aux ----------------
__global__ void scan_k(const int* __restrict__ cnt, int* __restrict__ offs,
                       const float* __restrict__ usage, float* __restrict__ aux) {
  if (threadIdx.x == 0 && blockIdx.x == 0) {
    int o = 0;
    for (int e = 0; e < E_NUM; ++e) { offs[e] = o; o += (cnt[e] + 127) & ~127; }
    offs[E_NUM] = o;
    float s = 0.f;
    for (int e = 0; e < E_NUM; ++e) { float m = usage[e] * (1.f / T_TOK); s += m * m; }
    *aux = (float)E_NUM * s;
  }
}

// ---------------- assignment: pair -> row ----------------
__global__ void assign_k(const int* __restrict__ topi, const int* __restrict__ offs,
                         int* __restrict__ cur, int* __restrict__ rowpair) {
  int p = blockIdx.x * 256 + threadIdx.x;
  int lane = threadIdx.x & 63;
  int e = topi[p];
  int r = 0;
#pragma unroll
  for (int ee = 0; ee < E_NUM; ++ee) {
    unsigned long long mask = __ballot(e == ee);
    if (e == ee) {
      int leader = __ffsll((unsigned long long)mask) - 1;
      int rank = __popcll(mask & ((1ull << lane) - 1ull));
      int b = 0;
      if (lane == leader) b = atomicAdd(&cur[ee], (int)__popcll(mask));
      b = __shfl(b, leader);
      r = offs[ee] + b + rank;
    }
  }
  rowpair[r] = p;
}

// ---------------- GEMM1: hseg = gelu(gather(xb) @ w1[e]^T) ----------------
// Swizzled LDS: element (row, col16-block c) stored at physical block c ^ (row&7).
// Achieved via XOR on the per-lane GLOBAL source address (gload_lds dest stays linear).
template <bool BPRE>
__global__ __launch_bounds__(256) void gemm1n_k(
    const unsigned short* __restrict__ xb, const void* __restrict__ w1v,
    const int* __restrict__ offs, const int* __restrict__ rowpair,
    const unsigned short* __restrict__ zrow,
    unsigned short* __restrict__ hseg, int segbase, int segrows) {
  int bid0 = blockIdx.x;
  int bid = ((bid0 & 7) << 11) | (bid0 >> 3);  // XCD chunk swizzle (grid 16384)
  int e = bid >> 11, rem = bid & 2047, mt = rem >> 4, nt = rem & 15;
  int rend = offs[e + 1];
  int rowbase = offs[e] + mt * 128;
  if (rowbase >= rend || rowbase < segbase || rowbase >= segbase + segrows) return;

  __shared__ short As[128 * 64];
  __shared__ short Bs[128 * 64];
  int tid = threadIdx.x, wid = tid >> 6, lane = tid & 63;
  int wm = wid >> 1, wn = wid & 1;
  int g4 = lane >> 4, c4 = (lane & 15) * 4;
  int srow = lane >> 3;                       // 0..7
  int swz = ((lane & 7) * 8) ^ (srow << 3);   // shorts: col ^ (row&7)<<3
  int rk = (lane & 7) << 3;                   // read-side XOR key (shorts)

  // A-gather bases: 4 chunks/thread, row = (i*4+wid)*8 + srow
  const unsigned short* abase[4];
#pragma unroll
  for (int i = 0; i < 4; ++i) {
    int p = rowpair[rowbase + (i * 4 + wid) * 8 + srow];
    abase[i] = (p >= 0) ? (xb + (size_t)(p >> 1) * D_DIM) : zrow;
  }
  const unsigned short* Bgb = (const unsigned short*)w1v + ((size_t)e * F_DIM + nt * 128) * D_DIM;
  const float* Bgf = (const float*)w1v + ((size_t)e * F_DIM + nt * 128) * D_DIM;

  f32x4 acc[4][4] = {};
  for (int ks = 0; ks < 16; ++ks) {
    int k0 = ks * 64;
#pragma unroll
    for (int i = 0; i < 4; ++i)
      gload16(abase[i] + k0 + swz, (short*)As + (i * 4 + wid) * 512);
    if (BPRE) {
#pragma unroll
      for (int i = 0; i < 4; ++i) {
        int chunk = i * 4 + wid;
        int row = chunk * 8 + srow;
        gload16(Bgb + (size_t)row * D_DIM + k0 + swz, (short*)Bs + chunk * 512);
      }
    } else {
#pragma unroll
      for (int i = 0; i < 8; ++i) {
        int row = i * 16 + wid * 4 + g4;
        float4 w = *(const float4*)(Bgf + (size_t)row * D_DIM + k0 + c4);
        uint2 uw; uw.x = pk2(w.x, w.y); uw.y = pk2(w.z, w.w);
        *(uint2*)&Bs[row * 64 + (c4 ^ ((row & 7) << 3))] = uw;
      }
    }
    __syncthreads();
    int ar = wm * 64 + (lane & 15), br = wn * 64 + (lane & 15);
#pragma unroll
    for (int kk = 0; kk < 2; ++kk) {
      int cs = (kk * 32 + g4 * 8) ^ rk;
      s16x8 a[4], b[4];
#pragma unroll
      for (int m = 0; m < 4; ++m) a[m] = *(const s16x8*)&As[(ar + m * 16) * 64 + cs];
#pragma unroll
      for (int n = 0; n < 4; ++n) b[n] = *(const s16x8*)&Bs[(br + n * 16) * 64 + cs];
#pragma unroll
      for (int m = 0; m < 4; ++m)
#pragma unroll
        for (int n = 0; n < 4; ++n)
          acc[m][n] = __builtin_amdgcn_mfma_f32_16x16x32_bf16(a[m], b[n], acc[m][n], 0, 0, 0);
    }
    __syncthreads();
  }
  int c0 = nt * 128 + wn * 64 + (lane & 15);
  int lr0 = wm * 64 + (g4 << 2);
  size_t rloc = (size_t)(rowbase - segbase);
#pragma unroll
  for (int m = 0; m < 4; ++m)
#pragma unroll
    for (int j = 0; j < 4; ++j) {
      size_t rr = (rloc + lr0 + m * 16 + j) * F_DIM;
#pragma unroll
      for (int n = 0; n < 4; ++n) {
        float v = acc[m][n][j];
        float g = 0.5f * v * (1.f + erff(v * 0.70710678118f));
        hseg[rr + c0 + n * 16] = f2b(g);
      }
    }
}

// ---------------- GEMM2: out[t] += w * (hseg @ w2[e]^T) ----------------
template <bool BPRE>
__global__ __launch_bounds__(256) void gemm2n_k(
    const unsigned short* __restrict__ hseg, const void* __restrict__ w2v,
    const int* __restrict__ offs, const int* __restrict__ rowpair,
    const float* __restrict__ topw, float* __restrict__ out,
    int segbase, int segrows) {
  int bid0 = blockIdx.x;
  int bid = ((bid0 & 7) << 10) | (bid0 >> 3);  // XCD chunk swizzle (grid 8192)
  int e = bid >> 10, rem = bid & 1023, mt = rem >> 3, nt = rem & 7;
  int rend = offs[e + 1];
  int rowbase = offs[e] + mt * 128;
  if (rowbase >= rend || rowbase < segbase || rowbase >= segbase + segrows) return;

  __shared__ short As[128 * 64];
  __shared__ short Bs[128 * 64];
  int tid = threadIdx.x, wid = tid >> 6, lane = tid & 63;
  int wm = wid >> 1, wn = wid & 1;
  int g4 = lane >> 4, c4 = (lane & 15) * 4;
  int srow = lane >> 3;
  int swz = ((lane & 7) * 8) ^ (srow << 3);
  int rk = (lane & 7) << 3;

  const unsigned short* Ag = hseg + (size_t)(rowbase - segbase) * F_DIM;
  const unsigned short* Bgb = (const unsigned short*)w2v + ((size_t)e * D_DIM + nt * 128) * F_DIM;
  const float* Bgf = (const float*)w2v + ((size_t)e * D_DIM + nt * 128) * F_DIM;

  f32x4 acc[4][4] = {};
  for (int ks = 0; ks < 32; ++ks) {
    int k0 = ks * 64;
#pragma unroll
    for (int i = 0; i < 4; ++i) {
      int chunk = i * 4 + wid;
      int row = chunk * 8 + srow;
      gload16(Ag + (size_t)row * F_DIM + k0 + swz, (short*)As + chunk * 512);
    }
    if (BPRE) {
#pragma unroll
      for (int i = 0; i < 4; ++i) {
        int chunk = i * 4 + wid;
        int row = chunk * 8 + srow;
        gload16(Bgb + (size_t)row * F_DIM + k0 + swz, (short*)Bs + chunk * 512);
      }
    } else {
#pragma unroll
      for (int i = 0; i < 8; ++i) {
        int row = i * 16 + wid * 4 + g4;
        float4 w = *(const float4*)(Bgf + (size_t)row * F_DIM + k0 + c4);
        uint2 uw; uw.x = pk2(w.x, w.y); uw.y = pk2(w.z, w.w);
        *(uint2*)&Bs[row * 64 + (c4 ^ ((row & 7) << 3))] = uw;
      }
    }
    __syncthreads();
    int ar = wm * 64 + (lane & 15), br = wn * 64 + (lane & 15);
#pragma unroll
    for (int kk = 0; kk < 2; ++kk) {
      int cs = (kk * 32 + g4 * 8) ^ rk;
      s16x8 a[4], b[4];
#pragma unroll
      for (int m = 0; m < 4; ++m) a[m] = *(const s16x8*)&As[(ar + m * 16) * 64 + cs];
#pragma unroll
      for (int n = 0; n < 4; ++n) b[n] = *(const s16x8*)&Bs[(br + n * 16) * 64 + cs];
#pragma unroll
      for (int m = 0; m < 4; ++m)
#pragma unroll
        for (int n = 0; n < 4; ++n)
          acc[m][n] = __builtin_amdgcn_mfma_f32_16x16x32_bf16(a[m], b[n], acc[m][n], 0, 0, 0);
    }
    __syncthreads();
  }
  int c0 = nt * 128 + wn * 64 + (lane & 15);
  int lr0 = wm * 64 + (g4 << 2);
#pragma unroll
  for (int m = 0; m < 4; ++m)
#pragma unroll
    for (int j = 0; j < 4; ++j) {
      int lr = lr0 + m * 16 + j;
      int p = rowpair[rowbase + lr];
      if (p >= 0) {
        float wgt = topw[p];
        float* op = out + (size_t)(p >> 1) * D_DIM + c0;
#pragma unroll
        for (int n = 0; n < 4; ++n) unsafeAtomicAdd(op + n * 16, wgt * acc[m][n][j]);
      }
    }
}

extern "C" void kernel_launch(void* const* d_in, const int* in_sizes, int n_in,
                              void* d_out, int out_size, void* d_ws, size_t ws_size,
                              hipStream_t stream) {
  const float* x  = (const float*)d_in[0];
  const float* wr = (const float*)d_in[1];
  const float* w1 = (const float*)d_in[2];
  const float* w2 = (const float*)d_in[3];
  float* out = (float*)d_out;

  char* ws = (char*)d_ws;
  int* cnt = (int*)ws;                 // [8]
  int* cur = cnt + 8;                  // [8]
  int* offs = cnt + 16;                // [9]
  float* usage = (float*)(cnt + 25);   // [8]
  unsigned short* zrow = (unsigned short*)(ws + 256);  // 2KB zero row
  size_t off = 256 + 2048;
  int*   topi = (int*)(ws + off);     off += (size_t)2 * T_TOK * 4;
  float* topw = (float*)(ws + off);   off += (size_t)2 * T_TOK * 4;
  int*   rowpair = (int*)(ws + off);  off += (size_t)ROWCAP * 4;
  float* probs8 = (float*)(ws + off); off += (size_t)T_TOK * 8 * 4;
  off = (off + 255) & ~(size_t)255;

  const size_t xbbytes = (size_t)T_TOK * D_DIM * 2;              // 33.6 MB
  const size_t wbytes  = (size_t)2 * E_NUM * F_DIM * D_DIM * 2;  // 67.1 MB
  const size_t minseg  = (size_t)4224 * F_DIM * 2;               // 17.3 MB

  if (ws_size < off + xbbytes + minseg) return;  // won't happen (ws >= ~136MB)
  unsigned short* xb = (unsigned short*)(ws + off); off += xbbytes;

  bool pre = false;
  unsigned short *w1b = nullptr, *w2b = nullptr;
  if (ws_size >= off + wbytes + minseg) {
    pre = true;
    w1b = (unsigned short*)(ws + off); off += wbytes / 2;
    w2b = (unsigned short*)(ws + off); off += wbytes / 2;
  }
  size_t avail = ws_size - off;
  size_t segcap = (avail / ((size_t)F_DIM * 2)) & ~(size_t)127;
  int segrows = segcap > (size_t)ROWCAP ? ROWCAP : (int)segcap;
  if (segrows < 128) return;
  unsigned short* hseg = (unsigned short*)(ws + off);
  int nseg = (ROWCAP + segrows - 1) / segrows;

  hipMemsetAsync(ws, 0, 2304, stream);
  hipMemsetAsync(rowpair, 0xFF, (size_t)ROWCAP * 4, stream);
  hipMemsetAsync(d_out, 0, (size_t)out_size * 4, stream);
  castx_k<<<T_TOK * D_DIM / 8 / 256, 256, 0, stream>>>(x, xb);
  if (pre) castw_k<<<16384, 256, 0, stream>>>(w1, w2, w1b, w2b);
  router_k<<<T_TOK / 4, 256, 0, stream>>>(x, wr, topi, topw, probs8);
  hist_k<<<64, 256, 0, stream>>>(topi, probs8, cnt, usage);
  scan_k<<<1, 64, 0, stream>>>(cnt, offs, usage, out + (size_t)T_TOK * D_DIM);
  assign_k<<<2 * T_TOK / 256, 256, 0, stream>>>(topi, offs, cur, rowpair);

  for (int s = 0; s < nseg; ++s) {
    int segbase = s * segrows;
    if (pre) {
      gemm1n_k<true><<<E_NUM * 2048, 256, 0, stream>>>(xb, w1b, offs, rowpair, zrow, hseg, segbase, segrows);
      gemm2n_k<true><<<E_NUM * 1024, 256, 0, stream>>>(hseg, w2b, offs, rowpair, topw, out, segbase, segrows);
    } else {
      gemm1n_k<false><<<E_NUM * 2048, 256, 0, stream>>>(xb, w1, offs, rowpair, zrow, hseg, segbase, segrows);
      gemm2n_k<false><<<E_NUM * 1024, 256, 0, stream>>>(hseg, w2, offs, rowpair, topw, out, segbase, segrows);
    }
  }
}

// Round 5
// 742.257 us; speedup vs baseline: 1.5449x; 1.0120x over previous
//
#include <hip/hip_runtime.h>
#include <hip/hip_bf16.h>
#include <math.h>

typedef __attribute__((ext_vector_type(8))) short s16x8;
typedef __attribute__((ext_vector_type(4))) float f32x4;

#define T_TOK 16384
#define D_DIM 1024
#define F_DIM 2048
#define E_NUM 8
#define RCAP 34816  // 2*T + 8*256 worst-case 256-padded rows
#define MAXTILE 136

__device__ __forceinline__ unsigned short f2b(float f) {
  unsigned u = __float_as_uint(f);
  u += 0x7fff + ((u >> 16) & 1);
  return (unsigned short)(u >> 16);
}
__device__ __forceinline__ unsigned pk2(float a, float b) {
  __hip_bfloat162 h = __float22bfloat162_rn(make_float2(a, b));
  return *reinterpret_cast<unsigned*>(&h);
}
__device__ __forceinline__ void gload16(const void* g, void* l) {
  __builtin_amdgcn_global_load_lds(
      (const __attribute__((address_space(1))) unsigned*)g,
      (__attribute__((address_space(3))) unsigned*)l, 16, 0, 0);
}

// ---------------- weight cast fp32 -> bf16 ----------------
__global__ void castw_k(const float* __restrict__ w1, const float* __restrict__ w2,
                        unsigned short* __restrict__ w1b, unsigned short* __restrict__ w2b) {
  size_t i = ((size_t)blockIdx.x * 256 + threadIdx.x) * 4;
  float4 a = *(const float4*)(w1 + i);
  float4 b = *(const float4*)(w2 + i);
  uint2 ua, ub;
  ua.x = pk2(a.x, a.y); ua.y = pk2(a.z, a.w);
  ub.x = pk2(b.x, b.y); ub.y = pk2(b.z, b.w);
  *(uint2*)(w1b + i) = ua;
  *(uint2*)(w2b + i) = ub;
}

// ---------------- router (+ fused x->bf16 cast): logits, softmax, top-2 ----------------
__global__ void router_k(const float* __restrict__ x, const float* __restrict__ wr,
                         int* __restrict__ topi, float* __restrict__ topw,
                         float* __restrict__ probs8, unsigned short* __restrict__ xb) {
  int tid = threadIdx.x, wid = tid >> 6, lane = tid & 63;
  int t = blockIdx.x * 4 + wid;
  const float* xr = x + (size_t)t * D_DIM;
  float4 xv[4];
#pragma unroll
  for (int i = 0; i < 4; ++i) xv[i] = *(const float4*)(xr + i * 256 + lane * 4);
  // fused bf16 cast of x
#pragma unroll
  for (int i = 0; i < 4; ++i) {
    uint2 u; u.x = pk2(xv[i].x, xv[i].y); u.y = pk2(xv[i].z, xv[i].w);
    *(uint2*)(xb + (size_t)t * D_DIM + i * 256 + lane * 4) = u;
  }
  float logit[E_NUM];
#pragma unroll
  for (int e = 0; e < E_NUM; ++e) {
    const float* wrow = wr + e * D_DIM;
    float p = 0.f;
#pragma unroll
    for (int i = 0; i < 4; ++i) {
      float4 wv = *(const float4*)(wrow + i * 256 + lane * 4);
      p += xv[i].x * wv.x + xv[i].y * wv.y + xv[i].z * wv.z + xv[i].w * wv.w;
    }
    for (int s = 32; s; s >>= 1) p += __shfl_xor(p, s);
    logit[e] = p;
  }
  if (lane == 0) {
    float m = logit[0];
    for (int e = 1; e < E_NUM; ++e) m = fmaxf(m, logit[e]);
    float pr[E_NUM];
    float sum = 0.f;
    for (int e = 0; e < E_NUM; ++e) { pr[e] = expf(logit[e] - m); sum += pr[e]; }
    float inv = 1.f / sum;
    for (int e = 0; e < E_NUM; ++e) { pr[e] *= inv; probs8[t * 8 + e] = pr[e]; }
    int i0 = 0;
    for (int e = 1; e < E_NUM; ++e) if (pr[e] > pr[i0]) i0 = e;
    int i1 = (i0 == 0) ? 1 : 0;
    for (int e = 0; e < E_NUM; ++e) if (e != i0 && pr[e] > pr[i1]) i1 = e;
    float wsum = pr[i0] + pr[i1];
    topi[2 * t] = i0;  topi[2 * t + 1] = i1;
    topw[2 * t] = pr[i0] / wsum;  topw[2 * t + 1] = pr[i1] / wsum;
  }
}

// ---------------- histogram ----------------
__global__ void hist_k(const int* __restrict__ topi, const float* __restrict__ probs8,
                       int* __restrict__ cnt, float* __restrict__ usage) {
  __shared__ int sc[E_NUM];
  __shared__ float su[E_NUM];
  int tid = threadIdx.x;
  if (tid < E_NUM) { sc[tid] = 0; su[tid] = 0.f; }
  __syncthreads();
  for (int i = blockIdx.x * 256 + tid; i < 2 * T_TOK; i += 256 * 64)
    atomicAdd(&sc[topi[i]], 1);
  for (int i = blockIdx.x * 256 + tid; i < 8 * T_TOK; i += 256 * 64)
    atomicAdd(&su[i & 7], probs8[i]);
  __syncthreads();
  if (tid < E_NUM) { atomicAdd(&cnt[tid], sc[tid]); atomicAdd(&usage[tid], su[tid]); }
}

// ---------------- offsets (256-padded) + tile table + aux ----------------
__global__ void scan_k(const int* __restrict__ cnt, int* __restrict__ offs,
                       int* __restrict__ tl_e, int* __restrict__ tl_rb, int* __restrict__ tlcnt,
                       const float* __restrict__ usage, float* __restrict__ aux) {
  if (threadIdx.x == 0 && blockIdx.x == 0) {
    int o = 0, n = 0;
    for (int e = 0; e < E_NUM; ++e) {
      offs[e] = o;
      int pe = (cnt[e] + 255) & ~255;
      for (int r = 0; r < pe; r += 256) { tl_e[n] = e; tl_rb[n] = o + r; ++n; }
      o += pe;
    }
    offs[E_NUM] = o;
    *tlcnt = n;
    float s = 0.f;
    for (int e = 0; e < E_NUM; ++e) { float m = usage[e] * (1.f / T_TOK); s += m * m; }
    *aux = (float)E_NUM * s;
  }
}

// ---------------- assignment: pair -> row ----------------
__global__ void assign_k(const int* __restrict__ topi, const int* __restrict__ offs,
                         int* __restrict__ cur, int* __restrict__ rowpair) {
  int p = blockIdx.x * 256 + threadIdx.x;
  int lane = threadIdx.x & 63;
  int e = topi[p];
  int r = 0;
#pragma unroll
  for (int ee = 0; ee < E_NUM; ++ee) {
    unsigned long long mask = __ballot(e == ee);
    if (e == ee) {
      int leader = __ffsll((unsigned long long)mask) - 1;
      int rank = __popcll(mask & ((1ull << lane) - 1ull));
      int b = 0;
      if (lane == leader) b = atomicAdd(&cur[ee], (int)__popcll(mask));
      b = __shfl(b, leader);
      r = offs[ee] + b + rank;
    }
  }
  rowpair[r] = p;
}

// ---------------- GEMM1: hseg = gelu(gather(xb) @ w1[e]^T) ----------------
// 256x256 tile, BK=64, 8 waves (2Mx4N), dbuf LDS 128KB, tile-ahead prefetch,
// 1 barrier per K-tile, XOR-swizzled LDS (source-side swizzle + read XOR).
__global__ __launch_bounds__(512, 2) void gemm1p_k(
    const unsigned short* __restrict__ xb, const unsigned short* __restrict__ w1b,
    const int* __restrict__ tl_e, const int* __restrict__ tl_rb, const int* __restrict__ tlcnt,
    const int* __restrict__ rowpair, const unsigned short* __restrict__ zrow,
    unsigned short* __restrict__ hseg, int segbase, int segrows) {
  int bid = blockIdx.x;
  int nt = bid & 7, tile = bid >> 3;
  if (tile >= *tlcnt) return;
  int e = tl_e[tile], rowbase = tl_rb[tile];
  if (rowbase < segbase || rowbase >= segbase + segrows) return;

  __shared__ short lds[2][2][256 * 64];  // [buf][A=0/B=1] = 128 KiB
  int tid = threadIdx.x, wid = tid >> 6, lane = tid & 63;
  int wm = wid >> 2, wn = wid & 3;
  int l8 = lane >> 3, j7 = lane & 7;
  int sg = ((j7 ^ l8) << 3);  // swizzled source granule offset (shorts)

  // A gather bases (4 staged rows per thread)
  const unsigned short* abase[4];
#pragma unroll
  for (int i = 0; i < 4; ++i) {
    int p = rowpair[rowbase + i * 64 + wid * 8 + l8];
    abase[i] = (p >= 0) ? (xb + (size_t)(p >> 1) * D_DIM) : zrow;
  }
  const unsigned short* Bg = w1b + ((size_t)e * F_DIM + nt * 256) * D_DIM + (size_t)(wid * 8 + l8) * D_DIM + sg;

  f32x4 acc[8][4] = {};
  int rl = lane & 15, g4 = lane >> 4;

  auto STAGE = [&](int buf, int k0) {
#pragma unroll
    for (int i = 0; i < 4; ++i)
      gload16(abase[i] + k0 + sg, &lds[buf][0][(i * 64 + wid * 8) * 64]);
#pragma unroll
    for (int i = 0; i < 4; ++i)
      gload16(Bg + (size_t)i * 64 * D_DIM + k0, &lds[buf][1][(i * 64 + wid * 8) * 64]);
  };
  auto COMP = [&](int buf) {
    const short* As = lds[buf][0];
    const short* Bs = lds[buf][1];
#pragma unroll
    for (int q = 0; q < 4; ++q) {
      int mq = q >> 1, nq = q & 1;
      s16x8 av[2][4], bv[2][2];
#pragma unroll
      for (int kk = 0; kk < 2; ++kk) {
        int gr = (((kk * 4 + g4) ^ j7) << 3);
#pragma unroll
        for (int mm = 0; mm < 4; ++mm)
          av[kk][mm] = *(const s16x8*)&As[(wm * 128 + mq * 64 + mm * 16 + rl) * 64 + gr];
#pragma unroll
        for (int nn = 0; nn < 2; ++nn)
          bv[kk][nn] = *(const s16x8*)&Bs[(wn * 64 + nq * 32 + nn * 16 + rl) * 64 + gr];
      }
      __builtin_amdgcn_s_setprio(1);
#pragma unroll
      for (int kk = 0; kk < 2; ++kk)
#pragma unroll
        for (int mm = 0; mm < 4; ++mm)
#pragma unroll
          for (int nn = 0; nn < 2; ++nn)
            acc[mq * 4 + mm][nq * 2 + nn] =
                __builtin_amdgcn_mfma_f32_16x16x32_bf16(av[kk][mm], bv[kk][nn],
                                                        acc[mq * 4 + mm][nq * 2 + nn], 0, 0, 0);
      __builtin_amdgcn_s_setprio(0);
    }
  };

  STAGE(0, 0);
  __syncthreads();
#pragma unroll 2
  for (int t = 0; t < 16; ++t) {
    int curb = t & 1;
    if (t < 15) STAGE(curb ^ 1, (t + 1) * 64);  // prefetch next tile BEFORE compute
    COMP(curb);
    __syncthreads();  // implicit vmcnt drain: next tile ready; buf reuse safe
  }

  size_t rloc = (size_t)(rowbase - segbase);
#pragma unroll
  for (int q = 0; q < 4; ++q) {
    int mq = q >> 1, nq = q & 1;
#pragma unroll
    for (int mm = 0; mm < 4; ++mm)
#pragma unroll
      for (int j = 0; j < 4; ++j) {
        size_t rr = (rloc + wm * 128 + mq * 64 + mm * 16 + g4 * 4 + j) * F_DIM;
#pragma unroll
        for (int nn = 0; nn < 2; ++nn) {
          float v = acc[mq * 4 + mm][nq * 2 + nn][j];
          float g = 0.5f * v * (1.f + erff(v * 0.70710678118f));
          hseg[rr + nt * 256 + wn * 64 + nq * 32 + nn * 16 + rl] = f2b(g);
        }
      }
  }
}

// ---------------- GEMM2: out[t] += w * (hseg @ w2[e]^T), atomic scatter ----------------
// 256x128 tile, BK=64, 8 waves (2Mx4N), dbuf LDS 96KB.
__global__ __launch_bounds__(512, 2) void gemm2p_k(
    const unsigned short* __restrict__ hseg, const unsigned short* __restrict__ w2b,
    const int* __restrict__ tl_e, const int* __restrict__ tl_rb, const int* __restrict__ tlcnt,
    const int* __restrict__ rowpair, const float* __restrict__ topw,
    float* __restrict__ out, int segbase, int segrows) {
  int bid = blockIdx.x;
  int nt = bid & 7, tile = bid >> 3;
  if (tile >= *tlcnt) return;
  int e = tl_e[tile], rowbase = tl_rb[tile];
  if (rowbase < segbase || rowbase >= segbase + segrows) return;

  __shared__ short ldsA[2][256 * 64];  // 64 KiB
  __shared__ short ldsB[2][128 * 64];  // 32 KiB
  int tid = threadIdx.x, wid = tid >> 6, lane = tid & 63;
  int wm = wid >> 2, wn = wid & 3;
  int l8 = lane >> 3, j7 = lane & 7;
  int sg = ((j7 ^ l8) << 3);

  const unsigned short* Ag = hseg + (size_t)(rowbase - segbase) * F_DIM + (size_t)(wid * 8 + l8) * F_DIM + sg;
  const unsigned short* Bg = w2b + ((size_t)e * D_DIM + nt * 128) * F_DIM + (size_t)(wid * 8 + l8) * F_DIM + sg;

  f32x4 acc[8][2] = {};
  int rl = lane & 15, g4 = lane >> 4;

  auto STAGE = [&](int buf, int k0) {
#pragma unroll
    for (int i = 0; i < 4; ++i)
      gload16(Ag + (size_t)i * 64 * F_DIM + k0, &ldsA[buf][(i * 64 + wid * 8) * 64]);
#pragma unroll
    for (int i = 0; i < 2; ++i)
      gload16(Bg + (size_t)i * 64 * F_DIM + k0, &ldsB[buf][(i * 64 + wid * 8) * 64]);
  };
  auto COMP = [&](int buf) {
    const short* As = ldsA[buf];
    const short* Bs = ldsB[buf];
#pragma unroll
    for (int q = 0; q < 2; ++q) {
      s16x8 av[2][4], bv[2][2];
#pragma unroll
      for (int kk = 0; kk < 2; ++kk) {
        int gr = (((kk * 4 + g4) ^ j7) << 3);
#pragma unroll
        for (int mm = 0; mm < 4; ++mm)
          av[kk][mm] = *(const s16x8*)&As[(wm * 128 + q * 64 + mm * 16 + rl) * 64 + gr];
#pragma unroll
        for (int nn = 0; nn < 2; ++nn)
          bv[kk][nn] = *(const s16x8*)&Bs[(wn * 32 + nn * 16 + rl) * 64 + gr];
      }
      __builtin_amdgcn_s_setprio(1);
#pragma unroll
      for (int kk = 0; kk < 2; ++kk)
#pragma unroll
        for (int mm = 0; mm < 4; ++mm)
#pragma unroll
          for (int nn = 0; nn < 2; ++nn)
            acc[q * 4 + mm][nn] =
                __builtin_amdgcn_mfma_f32_16x16x32_bf16(av[kk][mm], bv[kk][nn],
                                                        acc[q * 4 + mm][nn], 0, 0, 0);
      __builtin_amdgcn_s_setprio(0);
    }
  };

  STAGE(0, 0);
  __syncthreads();
#pragma unroll 2
  for (int t = 0; t < 32; ++t) {
    int curb = t & 1;
    if (t < 31) STAGE(curb ^ 1, (t + 1) * 64);
    COMP(curb);
    __syncthreads();
  }

#pragma unroll
  for (int q = 0; q < 2; ++q)
#pragma unroll
    for (int mm = 0; mm < 4; ++mm)
#pragma unroll
      for (int j = 0; j < 4; ++j) {
        int lr = wm * 128 + q * 64 + mm * 16 + g4 * 4 + j;
        int p = rowpair[rowbase + lr];
        if (p >= 0) {
          float wgt = topw[p];
          float* op = out + (size_t)(p >> 1) * D_DIM + nt * 128 + wn * 32 + rl;
#pragma unroll
          for (int nn = 0; nn < 2; ++nn)
            unsafeAtomicAdd(op + nn * 16, wgt * acc[q * 4 + mm][nn][j]);
        }
      }
}

extern "C" void kernel_launch(void* const* d_in, const int* in_sizes, int n_in,
                              void* d_out, int out_size, void* d_ws, size_t ws_size,
                              hipStream_t stream) {
  const float* x  = (const float*)d_in[0];
  const float* wr = (const float*)d_in[1];
  const float* w1 = (const float*)d_in[2];
  const float* w2 = (const float*)d_in[3];
  float* out = (float*)d_out;

  char* ws = (char*)d_ws;
  int* cnt   = (int*)ws;         // [8]
  int* cur   = cnt + 8;          // [8]
  int* offs  = cnt + 16;         // [9]
  int* tlcnt = cnt + 25;         // [1]
  int* tl_e  = cnt + 26;         // [136]
  int* tl_rb = cnt + 162;        // [136]
  float* usage = (float*)(cnt + 298);  // [8]
  unsigned short* zrow = (unsigned short*)(ws + 4096);  // 2KB zeros
  size_t off = 8192;
  int*   topi = (int*)(ws + off);     off += (size_t)2 * T_TOK * 4;
  float* topw = (float*)(ws + off);   off += (size_t)2 * T_TOK * 4;
  int*   rowpair = (int*)(ws + off);  off += (size_t)RCAP * 4;
  float* probs8 = (float*)(ws + off); off += (size_t)T_TOK * 8 * 4;
  off = (off + 255) & ~(size_t)255;

  unsigned short* xb = (unsigned short*)(ws + off);
  off += (size_t)T_TOK * D_DIM * 2;                       // 33.6 MB
  unsigned short* w1b = (unsigned short*)(ws + off);
  off += (size_t)E_NUM * F_DIM * D_DIM * 2;               // 33.6 MB
  unsigned short* w2b = (unsigned short*)(ws + off);
  off += (size_t)E_NUM * F_DIM * D_DIM * 2;               // 33.6 MB
  if (ws_size < off + (size_t)4096 * F_DIM * 2) return;   // need >= 16.8MB hseg
  size_t avail = ws_size - off;
  size_t segcap = (avail / ((size_t)F_DIM * 2)) & ~(size_t)255;
  int segrows = segcap > (size_t)RCAP ? RCAP : (int)segcap;
  unsigned short* hseg = (unsigned short*)(ws + off);
  int nseg = (RCAP + segrows - 1) / segrows;

  hipMemsetAsync(ws, 0, 8192, stream);
  hipMemsetAsync(rowpair, 0xFF, (size_t)RCAP * 4, stream);
  hipMemsetAsync(d_out, 0, (size_t)out_size * 4, stream);
  castw_k<<<16384, 256, 0, stream>>>(w1, w2, w1b, w2b);
  router_k<<<T_TOK / 4, 256, 0, stream>>>(x, wr, topi, topw, probs8, xb);
  hist_k<<<64, 256, 0, stream>>>(topi, probs8, cnt, usage);
  scan_k<<<1, 64, 0, stream>>>(cnt, offs, tl_e, tl_rb, tlcnt, usage, out + (size_t)T_TOK * D_DIM);
  assign_k<<<2 * T_TOK / 256, 256, 0, stream>>>(topi, offs, cur, rowpair);

  for (int s = 0; s < nseg; ++s) {
    int segbase = s * segrows;
    gemm1p_k<<<MAXTILE * 8, 512, 0, stream>>>(xb, w1b, tl_e, tl_rb, tlcnt, rowpair, zrow,
                                              hseg, segbase, segrows);
    gemm2p_k<<<MAXTILE * 8, 512, 0, stream>>>(hseg, w2b, tl_e, tl_rb, tlcnt, rowpair, topw,
                                              out, segbase, segrows);
  }
}

// Round 6
// 725.163 us; speedup vs baseline: 1.5813x; 1.0236x over previous
//
#include <hip/hip_runtime.h>
#include <hip/hip_bf16.h>
#include <math.h>

typedef __attribute__((ext_vector_type(8))) short s16x8;
typedef __attribute__((ext_vector_type(4))) float f32x4;

#define T_TOK 16384
#define D_DIM 1024
#define F_DIM 2048
#define E_NUM 8
#define RCAP 34816  // 2*T + 8*256 worst-case 256-padded rows
#define MAXTILE 136

__device__ __forceinline__ unsigned short f2b(float f) {
  unsigned u = __float_as_uint(f);
  u += 0x7fff + ((u >> 16) & 1);
  return (unsigned short)(u >> 16);
}
__device__ __forceinline__ unsigned pk2(float a, float b) {
  __hip_bfloat162 h = __float22bfloat162_rn(make_float2(a, b));
  return *reinterpret_cast<unsigned*>(&h);
}
__device__ __forceinline__ void gload16(const void* g, void* l) {
  __builtin_amdgcn_global_load_lds(
      (const __attribute__((address_space(1))) unsigned*)g,
      (__attribute__((address_space(3))) unsigned*)l, 16, 0, 0);
}

// ---------------- weight cast fp32 -> bf16 ----------------
__global__ void castw_k(const float* __restrict__ w1, const float* __restrict__ w2,
                        unsigned short* __restrict__ w1b, unsigned short* __restrict__ w2b) {
  size_t i = ((size_t)blockIdx.x * 256 + threadIdx.x) * 4;
  float4 a = *(const float4*)(w1 + i);
  float4 b = *(const float4*)(w2 + i);
  uint2 ua, ub;
  ua.x = pk2(a.x, a.y); ua.y = pk2(a.z, a.w);
  ub.x = pk2(b.x, b.y); ub.y = pk2(b.z, b.w);
  *(uint2*)(w1b + i) = ua;
  *(uint2*)(w2b + i) = ub;
}

// ---------------- router (+ fused x->bf16 cast): logits, softmax, top-2 ----------------
__global__ void router_k(const float* __restrict__ x, const float* __restrict__ wr,
                         int* __restrict__ topi, float* __restrict__ topw,
                         float* __restrict__ probs8, unsigned short* __restrict__ xb) {
  int tid = threadIdx.x, wid = tid >> 6, lane = tid & 63;
  int t = blockIdx.x * 4 + wid;
  const float* xr = x + (size_t)t * D_DIM;
  float4 xv[4];
#pragma unroll
  for (int i = 0; i < 4; ++i) xv[i] = *(const float4*)(xr + i * 256 + lane * 4);
#pragma unroll
  for (int i = 0; i < 4; ++i) {
    uint2 u; u.x = pk2(xv[i].x, xv[i].y); u.y = pk2(xv[i].z, xv[i].w);
    *(uint2*)(xb + (size_t)t * D_DIM + i * 256 + lane * 4) = u;
  }
  float logit[E_NUM];
#pragma unroll
  for (int e = 0; e < E_NUM; ++e) {
    const float* wrow = wr + e * D_DIM;
    float p = 0.f;
#pragma unroll
    for (int i = 0; i < 4; ++i) {
      float4 wv = *(const float4*)(wrow + i * 256 + lane * 4);
      p += xv[i].x * wv.x + xv[i].y * wv.y + xv[i].z * wv.z + xv[i].w * wv.w;
    }
    for (int s = 32; s; s >>= 1) p += __shfl_xor(p, s);
    logit[e] = p;
  }
  if (lane == 0) {
    float m = logit[0];
    for (int e = 1; e < E_NUM; ++e) m = fmaxf(m, logit[e]);
    float pr[E_NUM];
    float sum = 0.f;
    for (int e = 0; e < E_NUM; ++e) { pr[e] = expf(logit[e] - m); sum += pr[e]; }
    float inv = 1.f / sum;
    for (int e = 0; e < E_NUM; ++e) { pr[e] *= inv; probs8[t * 8 + e] = pr[e]; }
    int i0 = 0;
    for (int e = 1; e < E_NUM; ++e) if (pr[e] > pr[i0]) i0 = e;
    int i1 = (i0 == 0) ? 1 : 0;
    for (int e = 0; e < E_NUM; ++e) if (e != i0 && pr[e] > pr[i1]) i1 = e;
    float wsum = pr[i0] + pr[i1];
    topi[2 * t] = i0;  topi[2 * t + 1] = i1;
    topw[2 * t] = pr[i0] / wsum;  topw[2 * t + 1] = pr[i1] / wsum;
  }
}

// ---------------- histogram ----------------
__global__ void hist_k(const int* __restrict__ topi, const float* __restrict__ probs8,
                       int* __restrict__ cnt, float* __restrict__ usage) {
  __shared__ int sc[E_NUM];
  __shared__ float su[E_NUM];
  int tid = threadIdx.x;
  if (tid < E_NUM) { sc[tid] = 0; su[tid] = 0.f; }
  __syncthreads();
  for (int i = blockIdx.x * 256 + tid; i < 2 * T_TOK; i += 256 * 64)
    atomicAdd(&sc[topi[i]], 1);
  for (int i = blockIdx.x * 256 + tid; i < 8 * T_TOK; i += 256 * 64)
    atomicAdd(&su[i & 7], probs8[i]);
  __syncthreads();
  if (tid < E_NUM) { atomicAdd(&cnt[tid], sc[tid]); atomicAdd(&usage[tid], su[tid]); }
}

// ---------------- offsets (256-padded) + tile table + aux ----------------
__global__ void scan_k(const int* __restrict__ cnt, int* __restrict__ offs,
                       int* __restrict__ tl_e, int* __restrict__ tl_rb, int* __restrict__ tlcnt,
                       const float* __restrict__ usage, float* __restrict__ aux) {
  if (threadIdx.x == 0 && blockIdx.x == 0) {
    int o = 0, n = 0;
    for (int e = 0; e < E_NUM; ++e) {
      offs[e] = o;
      int pe = (cnt[e] + 255) & ~255;
      for (int r = 0; r < pe; r += 256) { tl_e[n] = e; tl_rb[n] = o + r; ++n; }
      o += pe;
    }
    offs[E_NUM] = o;
    *tlcnt = n;
    float s = 0.f;
    for (int e = 0; e < E_NUM; ++e) { float m = usage[e] * (1.f / T_TOK); s += m * m; }
    *aux = (float)E_NUM * s;
  }
}

// ---------------- assignment: pair -> row ----------------
__global__ void assign_k(const int* __restrict__ topi, const int* __restrict__ offs,
                         int* __restrict__ cur, int* __restrict__ rowpair) {
  int p = blockIdx.x * 256 + threadIdx.x;
  int lane = threadIdx.x & 63;
  int e = topi[p];
  int r = 0;
#pragma unroll
  for (int ee = 0; ee < E_NUM; ++ee) {
    unsigned long long mask = __ballot(e == ee);
    if (e == ee) {
      int leader = __ffsll((unsigned long long)mask) - 1;
      int rank = __popcll(mask & ((1ull << lane) - 1ull));
      int b = 0;
      if (lane == leader) b = atomicAdd(&cur[ee], (int)__popcll(mask));
      b = __shfl(b, leader);
      r = offs[ee] + b + rank;
    }
  }
  rowpair[r] = p;
}

// ---------------- GEMM1: hseg = gelu(gather(xb) @ w1[e]^T) ----------------
// 256x256 tile, BK=64, 8 waves, dbuf LDS 128KB, tile-ahead prefetch.
// XCD-affine decode: all 8 nt-blocks of a tile share d%8 -> same XCD L2.
__global__ __launch_bounds__(512, 2) void gemm1p_k(
    const unsigned short* __restrict__ xb, const unsigned short* __restrict__ w1b,
    const int* __restrict__ tl_e, const int* __restrict__ tl_rb, const int* __restrict__ tlcnt,
    const int* __restrict__ rowpair, const unsigned short* __restrict__ zrow,
    unsigned short* __restrict__ hseg, int segbase, int segrows) {
  int d = blockIdx.x;
  int tile = (d & 7) + 8 * (d >> 6);
  int nt = (d >> 3) & 7;
  if (tile >= *tlcnt) return;
  int e = tl_e[tile], rowbase = tl_rb[tile];
  if (rowbase < segbase || rowbase >= segbase + segrows) return;

  __shared__ short lds[2][2][256 * 64];  // [buf][A=0/B=1] = 128 KiB
  int tid = threadIdx.x, wid = tid >> 6, lane = tid & 63;
  int wm = wid >> 2, wn = wid & 3;
  int l8 = lane >> 3, j7 = lane & 7;
  int sg = ((j7 ^ l8) << 3);  // swizzled source granule offset (shorts)

  const unsigned short* abase[4];
#pragma unroll
  for (int i = 0; i < 4; ++i) {
    int p = rowpair[rowbase + i * 64 + wid * 8 + l8];
    abase[i] = (p >= 0) ? (xb + (size_t)(p >> 1) * D_DIM) : zrow;
  }
  const unsigned short* Bg = w1b + ((size_t)e * F_DIM + nt * 256) * D_DIM + (size_t)(wid * 8 + l8) * D_DIM + sg;

  f32x4 acc[8][4] = {};
  int rl = lane & 15, g4 = lane >> 4;

  auto STAGE = [&](int buf, int k0) {
#pragma unroll
    for (int i = 0; i < 4; ++i)
      gload16(abase[i] + k0 + sg, &lds[buf][0][(i * 64 + wid * 8) * 64]);
#pragma unroll
    for (int i = 0; i < 4; ++i)
      gload16(Bg + (size_t)i * 64 * D_DIM + k0, &lds[buf][1][(i * 64 + wid * 8) * 64]);
  };
  auto COMP = [&](int buf) {
    const short* As = lds[buf][0];
    const short* Bs = lds[buf][1];
#pragma unroll
    for (int q = 0; q < 4; ++q) {
      int mq = q >> 1, nq = q & 1;
      s16x8 av[2][4], bv[2][2];
#pragma unroll
      for (int kk = 0; kk < 2; ++kk) {
        int gr = (((kk * 4 + g4) ^ j7) << 3);
#pragma unroll
        for (int mm = 0; mm < 4; ++mm)
          av[kk][mm] = *(const s16x8*)&As[(wm * 128 + mq * 64 + mm * 16 + rl) * 64 + gr];
#pragma unroll
        for (int nn = 0; nn < 2; ++nn)
          bv[kk][nn] = *(const s16x8*)&Bs[(wn * 64 + nq * 32 + nn * 16 + rl) * 64 + gr];
      }
      __builtin_amdgcn_s_setprio(1);
#pragma unroll
      for (int kk = 0; kk < 2; ++kk)
#pragma unroll
        for (int mm = 0; mm < 4; ++mm)
#pragma unroll
          for (int nn = 0; nn < 2; ++nn)
            acc[mq * 4 + mm][nq * 2 + nn] =
                __builtin_amdgcn_mfma_f32_16x16x32_bf16(av[kk][mm], bv[kk][nn],
                                                        acc[mq * 4 + mm][nq * 2 + nn], 0, 0, 0);
      __builtin_amdgcn_s_setprio(0);
    }
  };

  STAGE(0, 0);
  __syncthreads();
#pragma unroll 2
  for (int t = 0; t < 16; ++t) {
    int curb = t & 1;
    if (t < 15) STAGE(curb ^ 1, (t + 1) * 64);
    COMP(curb);
    __syncthreads();
  }

  size_t rloc = (size_t)(rowbase - segbase);
#pragma unroll
  for (int q = 0; q < 4; ++q) {
    int mq = q >> 1, nq = q & 1;
#pragma unroll
    for (int mm = 0; mm < 4; ++mm)
#pragma unroll
      for (int j = 0; j < 4; ++j) {
        size_t rr = (rloc + wm * 128 + mq * 64 + mm * 16 + g4 * 4 + j) * F_DIM;
#pragma unroll
        for (int nn = 0; nn < 2; ++nn) {
          float v = acc[mq * 4 + mm][nq * 2 + nn][j];
          float g = 0.5f * v * (1.f + erff(v * 0.70710678118f));
          hseg[rr + nt * 256 + wn * 64 + nq * 32 + nn * 16 + rl] = f2b(g);
        }
      }
  }
}

// ---------------- GEMM2: out[t] += w * (hseg @ w2[e]^T), atomic scatter ----------------
// 256x128 tile, BK=64, 8 waves, dbuf LDS 96KB. Same XCD-affine decode.
__global__ __launch_bounds__(512, 2) void gemm2p_k(
    const unsigned short* __restrict__ hseg, const unsigned short* __restrict__ w2b,
    const int* __restrict__ tl_e, const int* __restrict__ tl_rb, const int* __restrict__ tlcnt,
    const int* __restrict__ rowpair, const float* __restrict__ topw,
    float* __restrict__ out, int segbase, int segrows) {
  int d = blockIdx.x;
  int tile = (d & 7) + 8 * (d >> 6);
  int nt = (d >> 3) & 7;
  if (tile >= *tlcnt) return;
  int e = tl_e[tile], rowbase = tl_rb[tile];
  if (rowbase < segbase || rowbase >= segbase + segrows) return;

  __shared__ short ldsA[2][256 * 64];  // 64 KiB
  __shared__ short ldsB[2][128 * 64];  // 32 KiB
  int tid = threadIdx.x, wid = tid >> 6, lane = tid & 63;
  int wm = wid >> 2, wn = wid & 3;
  int l8 = lane >> 3, j7 = lane & 7;
  int sg = ((j7 ^ l8) << 3);

  const unsigned short* Ag = hseg + (size_t)(rowbase - segbase) * F_DIM + (size_t)(wid * 8 + l8) * F_DIM + sg;
  const unsigned short* Bg = w2b + ((size_t)e * D_DIM + nt * 128) * F_DIM + (size_t)(wid * 8 + l8) * F_DIM + sg;

  f32x4 acc[8][2] = {};
  int rl = lane & 15, g4 = lane >> 4;

  auto STAGE = [&](int buf, int k0) {
#pragma unroll
    for (int i = 0; i < 4; ++i)
      gload16(Ag + (size_t)i * 64 * F_DIM + k0, &ldsA[buf][(i * 64 + wid * 8) * 64]);
#pragma unroll
    for (int i = 0; i < 2; ++i)
      gload16(Bg + (size_t)i * 64 * F_DIM + k0, &ldsB[buf][(i * 64 + wid * 8) * 64]);
  };
  auto COMP = [&](int buf) {
    const short* As = ldsA[buf];
    const short* Bs = ldsB[buf];
#pragma unroll
    for (int q = 0; q < 2; ++q) {
      s16x8 av[2][4], bv[2][2];
#pragma unroll
      for (int kk = 0; kk < 2; ++kk) {
        int gr = (((kk * 4 + g4) ^ j7) << 3);
#pragma unroll
        for (int mm = 0; mm < 4; ++mm)
          av[kk][mm] = *(const s16x8*)&As[(wm * 128 + q * 64 + mm * 16 + rl) * 64 + gr];
#pragma unroll
        for (int nn = 0; nn < 2; ++nn)
          bv[kk][nn] = *(const s16x8*)&Bs[(wn * 32 + nn * 16 + rl) * 64 + gr];
      }
      __builtin_amdgcn_s_setprio(1);
#pragma unroll
      for (int kk = 0; kk < 2; ++kk)
#pragma unroll
        for (int mm = 0; mm < 4; ++mm)
#pragma unroll
          for (int nn = 0; nn < 2; ++nn)
            acc[q * 4 + mm][nn] =
                __builtin_amdgcn_mfma_f32_16x16x32_bf16(av[kk][mm], bv[kk][nn],
                                                        acc[q * 4 + mm][nn], 0, 0, 0);
      __builtin_amdgcn_s_setprio(0);
    }
  };

  STAGE(0, 0);
  __syncthreads();
#pragma unroll 2
  for (int t = 0; t < 32; ++t) {
    int curb = t & 1;
    if (t < 31) STAGE(curb ^ 1, (t + 1) * 64);
    COMP(curb);
    __syncthreads();
  }

#pragma unroll
  for (int q = 0; q < 2; ++q)
#pragma unroll
    for (int mm = 0; mm < 4; ++mm)
#pragma unroll
      for (int j = 0; j < 4; ++j) {
        int lr = wm * 128 + q * 64 + mm * 16 + g4 * 4 + j;
        int p = rowpair[rowbase + lr];
        if (p >= 0) {
          float wgt = topw[p];
          float* op = out + (size_t)(p >> 1) * D_DIM + nt * 128 + wn * 32 + rl;
#pragma unroll
          for (int nn = 0; nn < 2; ++nn)
            unsafeAtomicAdd(op + nn * 16, wgt * acc[q * 4 + mm][nn][j]);
        }
      }
}

extern "C" void kernel_launch(void* const* d_in, const int* in_sizes, int n_in,
                              void* d_out, int out_size, void* d_ws, size_t ws_size,
                              hipStream_t stream) {
  const float* x  = (const float*)d_in[0];
  const float* wr = (const float*)d_in[1];
  const float* w1 = (const float*)d_in[2];
  const float* w2 = (const float*)d_in[3];
  float* out = (float*)d_out;

  char* ws = (char*)d_ws;
  int* cnt   = (int*)ws;         // [8]
  int* cur   = cnt + 8;          // [8]
  int* offs  = cnt + 16;         // [9]
  int* tlcnt = cnt + 25;         // [1]
  int* tl_e  = cnt + 26;         // [136]
  int* tl_rb = cnt + 162;        // [136]
  float* usage = (float*)(cnt + 298);  // [8]
  unsigned short* zrow = (unsigned short*)(ws + 4096);  // 2KB zeros
  size_t off = 8192;
  int*   topi = (int*)(ws + off);     off += (size_t)2 * T_TOK * 4;
  float* topw = (float*)(ws + off);   off += (size_t)2 * T_TOK * 4;
  int*   rowpair = (int*)(ws + off);  off += (size_t)RCAP * 4;
  float* probs8 = (float*)(ws + off); off += (size_t)T_TOK * 8 * 4;
  off = (off + 255) & ~(size_t)255;

  unsigned short* xb = (unsigned short*)(ws + off);
  off += (size_t)T_TOK * D_DIM * 2;                       // 33.6 MB
  unsigned short* w1b = (unsigned short*)(ws + off);
  off += (size_t)E_NUM * F_DIM * D_DIM * 2;               // 33.6 MB
  unsigned short* w2b = (unsigned short*)(ws + off);
  off += (size_t)E_NUM * F_DIM * D_DIM * 2;               // 33.6 MB
  if (ws_size < off + (size_t)4096 * F_DIM * 2) return;   // need >= 16.8MB hseg
  size_t avail = ws_size - off;
  size_t segcap = (avail / ((size_t)F_DIM * 2)) & ~(size_t)255;
  int segrows = segcap > (size_t)RCAP ? RCAP : (int)segcap;
  unsigned short* hseg = (unsigned short*)(ws + off);
  int nseg = (RCAP + segrows - 1) / segrows;

  hipMemsetAsync(ws, 0, 8192, stream);
  hipMemsetAsync(rowpair, 0xFF, (size_t)RCAP * 4, stream);
  hipMemsetAsync(d_out, 0, (size_t)out_size * 4, stream);
  castw_k<<<16384, 256, 0, stream>>>(w1, w2, w1b, w2b);
  router_k<<<T_TOK / 4, 256, 0, stream>>>(x, wr, topi, topw, probs8, xb);
  hist_k<<<64, 256, 0, stream>>>(topi, probs8, cnt, usage);
  scan_k<<<1, 64, 0, stream>>>(cnt, offs, tl_e, tl_rb, tlcnt, usage, out + (size_t)T_TOK * D_DIM);
  assign_k<<<2 * T_TOK / 256, 256, 0, stream>>>(topi, offs, cur, rowpair);

  for (int s = 0; s < nseg; ++s) {
    int segbase = s * segrows;
    gemm1p_k<<<MAXTILE * 8, 512, 0, stream>>>(xb, w1b, tl_e, tl_rb, tlcnt, rowpair, zrow,
                                              hseg, segbase, segrows);
    gemm2p_k<<<MAXTILE * 8, 512, 0, stream>>>(hseg, w2b, tl_e, tl_rb, tlcnt, rowpair, topw,
                                              out, segbase, segrows);
  }
}